// Round 5
// baseline (372.760 us; speedup 1.0000x reference)
//
#include <hip/hip_runtime.h>
#include <math.h>

#define F_IN   128
#define HIDC   32
#define NHEAD  4
#define CDIM   40
#define NEG_SLOPE 0.2f
#define BCAP   4096
#define OVCAP  16384
#define SCHUNK 4096

typedef __attribute__((ext_vector_type(8))) short bf16x8;   // 8 bf16 = 4 VGPRs
typedef __attribute__((ext_vector_type(4))) float f32x4;    // MFMA C/D

__device__ __forceinline__ float leakyf(float x) { return x > 0.f ? x : NEG_SLOPE * x; }

__device__ __forceinline__ float sel4(float4 v, int h) {
    return (h == 0) ? v.x : (h == 1) ? v.y : (h == 2) ? v.z : v.w;
}
__device__ __forceinline__ unsigned pack2_bf16(float a, float b) {
    unsigned ua = __float_as_uint(a);
    unsigned ub = __float_as_uint(b);
    ua = (ua + 0x7FFFu + ((ua >> 16) & 1u)) >> 16;
    ub = (ub + 0x7FFFu + ((ub >> 16) & 1u)) >> 16;
    return ua | (ub << 16);
}
__device__ __forceinline__ float2 unpack2_bf16(unsigned p) {
    return make_float2(__uint_as_float(p << 16), __uint_as_float(p & 0xFFFF0000u));
}

// ---- W pre-pack into MFMA B-fragment order + bcnt zeroing -----------------
// (absorbs the hipMemsetAsync dispatch; runs before the CSR build)
__global__ void wb_prep_kernel(const float* __restrict__ Wg, const float* __restrict__ Wc,
                               uint4* __restrict__ wbf, unsigned* __restrict__ bcnt,
                               int nbuck1)
{
    int b = blockIdx.x;            // nt*4 + ks, 0..39
    int lane = threadIdx.x;        // 0..63
    int gtid = b * 64 + lane;
    if (gtid < nbuck1) bcnt[gtid] = 0u;
    int nt = b >> 2, ks = b & 3;
    int c = nt * 16 + (lane & 15);
    int k0 = ks * 32 + (lane >> 4) * 8;
    unsigned u[4];
#pragma unroll
    for (int jj = 0; jj < 4; ++jj) {
        int k = k0 + 2 * jj;
        float a0 = (c < 128) ? Wg[(size_t)k * 128 + c] : Wc[(size_t)k * 32 + (c - 128)];
        float a1 = (c < 128) ? Wg[(size_t)(k + 1) * 128 + c] : Wc[(size_t)(k + 1) * 32 + (c - 128)];
        u[jj] = pack2_bf16(a0, a1);
    }
    wbf[(size_t)b * 64 + lane] = make_uint4(u[0], u[1], u[2], u[3]);
}

// ---- first-layer GEMM on MFMA + fused logits1 epilogue --------------------
// Output row layout: hb[node][80] unsigned = 64 GAT (128ch bf16) + 16 GCN (32ch bf16)
__global__ __launch_bounds__(256) void gemm1_mfma_kernel(
    const float* __restrict__ X, const uint4* __restrict__ wbf,
    const float* __restrict__ aw_s, const float* __restrict__ aw_d,
    unsigned* __restrict__ hb,
    float* __restrict__ as1, float* __restrict__ ad1, int n)
{
    __shared__ float Ct[64][164];
    __shared__ float sw[128], dw[128];
    const int tid = threadIdx.x;
    const int w = tid >> 6, lane = tid & 63;
    const int m = lane & 15, q = lane >> 4;
    const int node0 = blockIdx.x * 64;
    if (tid < 128) { sw[tid] = aw_s[tid]; dw[tid] = aw_d[tid]; }

    f32x4 acc[10];
#pragma unroll
    for (int t = 0; t < 10; ++t) acc[t] = (f32x4){0.f, 0.f, 0.f, 0.f};

    const int row = node0 + w * 16 + m;
    const bool rv = row < n;
#pragma unroll
    for (int ks = 0; ks < 4; ++ks) {
        uint4 pa = make_uint4(0u, 0u, 0u, 0u);
        if (rv) {
            const float* xr = X + (size_t)row * 128 + ks * 32 + q * 8;
            float4 a0 = *(const float4*)xr;
            float4 a1 = *(const float4*)(xr + 4);
            pa = make_uint4(pack2_bf16(a0.x, a0.y), pack2_bf16(a0.z, a0.w),
                            pack2_bf16(a1.x, a1.y), pack2_bf16(a1.z, a1.w));
        }
        bf16x8 af = *(bf16x8*)&pa;
#pragma unroll
        for (int nt = 0; nt < 10; ++nt) {
            uint4 pb = wbf[(size_t)(nt * 4 + ks) * 64 + lane];
            bf16x8 bfv = *(bf16x8*)&pb;
            acc[nt] = __builtin_amdgcn_mfma_f32_16x16x32_bf16(af, bfv, acc[nt], 0, 0, 0);
        }
    }
#pragma unroll
    for (int nt = 0; nt < 10; ++nt)
#pragma unroll
        for (int r = 0; r < 4; ++r)
            Ct[w * 16 + q * 4 + r][nt * 16 + m] = acc[nt][r];
    __syncthreads();

    for (int i = tid; i < 64 * 64; i += 256) {
        int nd = i >> 6, u = i & 63;
        int gn = node0 + nd;
        if (gn < n)
            hb[(size_t)gn * 80 + u] = pack2_bf16(Ct[nd][2 * u], Ct[nd][2 * u + 1]);
    }
    for (int i = tid; i < 64 * 16; i += 256) {
        int nd = i >> 4, u = i & 15;
        int gn = node0 + nd;
        if (gn < n)
            hb[(size_t)gn * 80 + 64 + u] = pack2_bf16(Ct[nd][128 + 2 * u], Ct[nd][128 + 2 * u + 1]);
    }
    {
        int nd = tid >> 2, h = tid & 3;
        int gn = node0 + nd;
        if (gn < n) {
            float s = 0.f, d = 0.f;
#pragma unroll
            for (int k = 0; k < HIDC; ++k) {
                float v = Ct[nd][h * HIDC + k];
                s = fmaf(v, sw[h * HIDC + k], s);
                d = fmaf(v, dw[h * HIDC + k], d);
            }
            as1[(size_t)gn * 4 + h] = s;
            ad1[(size_t)gn * 4 + h] = d;
        }
    }
}

// bf16-in (packed), bf16-out variant (gcn L2 gemm)
template<int K, int OUTC, int BN, int BK, int OSTRIDE_U, int OFF_U>
__global__ __launch_bounds__((OUTC / 4) * (BN / 4)) void gemm_tile_bb(
    const unsigned* __restrict__ Xb, const float* __restrict__ W,
    unsigned* __restrict__ Yb, int n)
{
    constexpr int CG = OUTC / 4;
    constexpr int NG = BN / 4;
    constexpr int NT = CG * NG;
    __shared__ float Xs[BK][BN + 4];
    __shared__ float Ws[BK][OUTC];
    const int tid = threadIdx.x;
    const int cg = tid % CG, ng = tid / CG;
    const int node0 = blockIdx.x * BN;
    float acc[4][4] = {};

    for (int kb = 0; kb < K; kb += BK) {
        for (int idx = tid; idx < BN * (BK / 8); idx += NT) {
            int nd = idx / (BK / 8);
            int kq = idx % (BK / 8);
            int gnode = node0 + nd;
            uint4 v = (gnode < n) ? *(const uint4*)&Xb[(size_t)gnode * (K / 2) + kb / 2 + kq * 4]
                                  : make_uint4(0u, 0u, 0u, 0u);
            float2 a = unpack2_bf16(v.x), b = unpack2_bf16(v.y);
            float2 c = unpack2_bf16(v.z), d = unpack2_bf16(v.w);
            Xs[kq * 8 + 0][nd] = a.x; Xs[kq * 8 + 1][nd] = a.y;
            Xs[kq * 8 + 2][nd] = b.x; Xs[kq * 8 + 3][nd] = b.y;
            Xs[kq * 8 + 4][nd] = c.x; Xs[kq * 8 + 5][nd] = c.y;
            Xs[kq * 8 + 6][nd] = d.x; Xs[kq * 8 + 7][nd] = d.y;
        }
        for (int idx = tid; idx < BK * CG; idx += NT) {
            int kk = idx / CG;
            int cq = idx % CG;
            *(float4*)&Ws[kk][cq * 4] = *(const float4*)&W[(size_t)(kb + kk) * OUTC + cq * 4];
        }
        __syncthreads();
#pragma unroll
        for (int k = 0; k < BK; ++k) {
            float4 xv = *(const float4*)&Xs[k][ng * 4];
            float4 wv = *(const float4*)&Ws[k][cg * 4];
            float xa[4] = {xv.x, xv.y, xv.z, xv.w};
            float wa[4] = {wv.x, wv.y, wv.z, wv.w};
#pragma unroll
            for (int j = 0; j < 4; ++j)
#pragma unroll
                for (int c = 0; c < 4; ++c)
                    acc[j][c] = fmaf(xa[j], wa[c], acc[j][c]);
        }
        __syncthreads();
    }

#pragma unroll
    for (int j = 0; j < 4; ++j) {
        int gnode = node0 + ng * 4 + j;
        if (gnode < n) {
            uint2 pb = make_uint2(pack2_bf16(acc[j][0], acc[j][1]),
                                  pack2_bf16(acc[j][2], acc[j][3]));
            *(uint2*)&Yb[(size_t)gnode * OSTRIDE_U + OFF_U + cg * 2] = pb;
        }
    }
}

// ---- GAT L2 GEMM (bf16 in/out) + fused logits2 epilogue --------------------
__global__ __launch_bounds__(320) void gemm2_gat_kernel(
    const unsigned* __restrict__ Xb, const float* __restrict__ W,
    const float* __restrict__ aw_s, const float* __restrict__ aw_d,
    unsigned* __restrict__ Yb, float* __restrict__ as2, float* __restrict__ ad2, int n)
{
    constexpr int K = 128, OUTC = 40, BN = 128, BK = 32;
    constexpr int CG = OUTC / 4, NT = 320;
    __shared__ float smem[32 * 132 + 32 * 40];     // 5504 floats
    float* Xs = smem;                               // [32][132]
    float* Ws = smem + 32 * 132;                    // [32][40]
    const int tid = threadIdx.x;
    const int cg = tid % CG, ng = tid / CG;
    const int node0 = blockIdx.x * BN;
    float acc[4][4] = {};

    for (int kb = 0; kb < K; kb += BK) {
        for (int idx = tid; idx < BN * (BK / 8); idx += NT) {
            int nd = idx / (BK / 8);
            int kq = idx % (BK / 8);
            int gnode = node0 + nd;
            uint4 v = (gnode < n) ? *(const uint4*)&Xb[(size_t)gnode * (K / 2) + kb / 2 + kq * 4]
                                  : make_uint4(0u, 0u, 0u, 0u);
            float2 a = unpack2_bf16(v.x), b = unpack2_bf16(v.y);
            float2 c = unpack2_bf16(v.z), d = unpack2_bf16(v.w);
            Xs[(kq * 8 + 0) * 132 + nd] = a.x; Xs[(kq * 8 + 1) * 132 + nd] = a.y;
            Xs[(kq * 8 + 2) * 132 + nd] = b.x; Xs[(kq * 8 + 3) * 132 + nd] = b.y;
            Xs[(kq * 8 + 4) * 132 + nd] = c.x; Xs[(kq * 8 + 5) * 132 + nd] = c.y;
            Xs[(kq * 8 + 6) * 132 + nd] = d.x; Xs[(kq * 8 + 7) * 132 + nd] = d.y;
        }
        for (int idx = tid; idx < BK * CG; idx += NT) {
            int kk = idx / CG;
            int cq = idx % CG;
            *(float4*)&Ws[kk * 40 + cq * 4] = *(const float4*)&W[(size_t)(kb + kk) * OUTC + cq * 4];
        }
        __syncthreads();
#pragma unroll
        for (int k = 0; k < BK; ++k) {
            float4 xv = *(const float4*)&Xs[k * 132 + ng * 4];
            float4 wv = *(const float4*)&Ws[k * 40 + cg * 4];
            float xa[4] = {xv.x, xv.y, xv.z, xv.w};
            float wa[4] = {wv.x, wv.y, wv.z, wv.w};
#pragma unroll
            for (int j = 0; j < 4; ++j)
#pragma unroll
                for (int c = 0; c < 4; ++c)
                    acc[j][c] = fmaf(xa[j], wa[c], acc[j][c]);
        }
        __syncthreads();
    }

    // global bf16 write + stage Ct for logits
    float* Ct  = smem;              // [128][41]
    float* sww = smem + 128 * 41;   // [40]
    float* dww = sww + 40;          // [40]
#pragma unroll
    for (int j = 0; j < 4; ++j) {
        int gnode = node0 + ng * 4 + j;
        if (gnode < n) {
            uint2 pb = make_uint2(pack2_bf16(acc[j][0], acc[j][1]),
                                  pack2_bf16(acc[j][2], acc[j][3]));
            *(uint2*)&Yb[(size_t)gnode * 40 + cg * 2] = pb;
        }
#pragma unroll
        for (int c = 0; c < 4; ++c)
            Ct[(ng * 4 + j) * 41 + cg * 4 + c] = acc[j][c];
    }
    if (tid < 40) { sww[tid] = aw_s[tid]; dww[tid] = aw_d[tid]; }
    __syncthreads();
    if (tid < 128) {
        int gnode = node0 + tid;
        if (gnode < n) {
            float s = 0.f, d = 0.f;
#pragma unroll
            for (int c = 0; c < 40; ++c) {
                float v = Ct[tid * 41 + c];
                s = fmaf(v, sww[c], s);
                d = fmaf(v, dww[c], d);
            }
            as2[gnode] = s;
            ad2[gnode] = d;
        }
    }
}

// ---------------- CSR build: bucketed counting sort by dst ------------------
__global__ __launch_bounds__(256) void bucket_scatter_kernel(
    const int* __restrict__ src, const int* __restrict__ dst,
    unsigned* __restrict__ bcnt, unsigned* __restrict__ bpair,
    unsigned* __restrict__ ovf_cnt, uint2* __restrict__ ovf, int e, int nbuck)
{
    __shared__ unsigned hist[512];
    __shared__ unsigned base[512];
    const int t = threadIdx.x;
    const int lo = blockIdx.x * SCHUNK;
    const int hi = min(lo + SCHUNK, e);
    for (int i = t; i < nbuck; i += 256) hist[i] = 0;
    __syncthreads();
    for (int i = lo + t; i < hi; i += 256)
        atomicAdd(&hist[((unsigned)dst[i]) >> 7], 1u);
    __syncthreads();
    for (int i = t; i < nbuck; i += 256) {
        unsigned c = hist[i];
        base[i] = c ? atomicAdd(&bcnt[i], c) : 0u;
        hist[i] = 0;
    }
    __syncthreads();
    for (int i = lo + t; i < hi; i += 256) {
        unsigned s = (unsigned)src[i], d = (unsigned)dst[i];
        unsigned b = d >> 7;
        unsigned pos = base[b] + atomicAdd(&hist[b], 1u);
        if (pos < BCAP) bpair[(size_t)b * BCAP + pos] = s | ((d & 127u) << 16);
        else {
            unsigned o = atomicAdd(ovf_cnt, 1u);
            if (o < OVCAP) ovf[o] = make_uint2(s, d);
        }
    }
}

__global__ __launch_bounds__(256) void bucket_count_kernel(
    const unsigned* __restrict__ bcnt, const unsigned* __restrict__ bpair,
    const unsigned* __restrict__ ovf_cnt, const uint2* __restrict__ ovf,
    unsigned* __restrict__ counts, int n)
{
    __shared__ unsigned lc[128];
    const int b = blockIdx.x, base = b << 7;
    if (threadIdx.x < 128) lc[threadIdx.x] = 0;
    __syncthreads();
    unsigned bc = bcnt[b];
    int cnt = (int)(bc < BCAP ? bc : BCAP);
    for (int k = threadIdx.x; k < cnt; k += 256)
        atomicAdd(&lc[bpair[(size_t)b * BCAP + k] >> 16], 1u);
    unsigned oc_u = *ovf_cnt;
    int oc = (int)(oc_u < OVCAP ? oc_u : OVCAP);
    for (int k = threadIdx.x; k < oc; k += 256) {
        uint2 pp = ovf[k];
        if ((int)(pp.y >> 7) == b) atomicAdd(&lc[pp.y & 127u], 1u);
    }
    __syncthreads();
    int i = base + threadIdx.x;
    if (threadIdx.x < 128 && i < n) counts[i] = lc[threadIdx.x];
}

__global__ __launch_bounds__(256) void scan_reduce_kernel(const unsigned* __restrict__ counts,
                                                          unsigned* __restrict__ partials, int n)
{
    __shared__ unsigned sm[256];
    int t = threadIdx.x;
    int i = blockIdx.x * 256 + t;
    unsigned v = (i < n) ? counts[i] : 0u;
    sm[t] = v;
    __syncthreads();
#pragma unroll
    for (int off = 128; off > 0; off >>= 1) {
        if (t < off) sm[t] += sm[t + off];
        __syncthreads();
    }
    if (t == 0) partials[blockIdx.x] = sm[0];
}

__global__ __launch_bounds__(256) void scan_partials_kernel(unsigned* __restrict__ partials,
                                                            unsigned* __restrict__ rs, int nb, int n)
{
    __shared__ unsigned sm[256];
    int t = threadIdx.x;
    unsigned v = (t < nb) ? partials[t] : 0u;
    sm[t] = v;
    __syncthreads();
#pragma unroll
    for (int off = 1; off < 256; off <<= 1) {
        unsigned u = (t >= off) ? sm[t - off] : 0u;
        __syncthreads();
        sm[t] += u;
        __syncthreads();
    }
    if (t < nb) partials[t] = sm[t] - v;
    if (t == 255) rs[n] = sm[255];
}

__global__ __launch_bounds__(256) void scan_write_kernel(const unsigned* __restrict__ counts,
                                                         const unsigned* __restrict__ partials,
                                                         unsigned* __restrict__ rs,
                                                         float* __restrict__ nrm, int n)
{
    __shared__ unsigned sm[256];
    int t = threadIdx.x;
    int i = blockIdx.x * 256 + t;
    unsigned c = (i < n) ? counts[i] : 0u;
    sm[t] = c;
    __syncthreads();
#pragma unroll
    for (int off = 1; off < 256; off <<= 1) {
        unsigned u = (t >= off) ? sm[t - off] : 0u;
        __syncthreads();
        sm[t] += u;
        __syncthreads();
    }
    if (i < n) {
        rs[i] = partials[blockIdx.x] + sm[t] - c;
        nrm[i] = rsqrtf((float)(c + 1u));
    }
}

__global__ __launch_bounds__(256) void bucket_place_kernel(
    const unsigned* __restrict__ bcnt, const unsigned* __restrict__ bpair,
    const unsigned* __restrict__ rs, unsigned* __restrict__ csr_src,
    unsigned* __restrict__ cursor, int n)
{
    __shared__ unsigned lc[128];
    __shared__ unsigned rbase[128];
    const int b = blockIdx.x, base = b << 7;
    if (threadIdx.x < 128) {
        lc[threadIdx.x] = 0;
        int i = base + threadIdx.x;
        rbase[threadIdx.x] = (i < n) ? rs[i] : 0u;
    }
    __syncthreads();
    unsigned bc = bcnt[b];
    int cnt = (int)(bc < BCAP ? bc : BCAP);
    for (int k = threadIdx.x; k < cnt; k += 256) {
        unsigned v = bpair[(size_t)b * BCAP + k];
        unsigned ld = v >> 16;
        unsigned r = atomicAdd(&lc[ld], 1u);
        csr_src[rbase[ld] + r] = v & 0xFFFFu;
    }
    __syncthreads();
    int i = base + threadIdx.x;
    if (threadIdx.x < 128 && i < n) cursor[i] = rbase[threadIdx.x] + lc[threadIdx.x];
}

__global__ void overflow_fill_kernel(const unsigned* __restrict__ ovf_cnt,
                                     const uint2* __restrict__ ovf,
                                     unsigned* __restrict__ cursor,
                                     unsigned* __restrict__ csr_src)
{
    unsigned oc_u = *ovf_cnt;
    int oc = (int)(oc_u < OVCAP ? oc_u : OVCAP);
    for (int k = threadIdx.x; k < oc; k += 256) {
        uint2 pp = ovf[k];
        unsigned pos = atomicAdd(&cursor[pp.y], 1u);
        csr_src[pos] = pp.x;
    }
}

// -------- fused layer-1 aggregation: single-pass, LDS-free (R2 config) ------
// One wave per node, 2-deep pipeline (8 edges in flight), 36 VGPR / 62% occ.
// This config sits at the measured random-gather BW floor (~2.6 TB/s on
// ~146 MB); deeper pipes / 2-node / LDS variants all regress or tie.
__global__ __launch_bounds__(256) void agg1_fused_kernel(
    const unsigned* __restrict__ hb,
    const float* __restrict__ as1, const float* __restrict__ ad1,
    const float* __restrict__ nrm,
    const unsigned* __restrict__ rs, const unsigned* __restrict__ csr_src,
    const float* __restrict__ gat_b1, const float* __restrict__ gcn_b1,
    unsigned* __restrict__ xgb, unsigned* __restrict__ gaccb, int n)
{
    const int wid = threadIdx.x >> 6;
    const int lane = threadIdx.x & 63;
    const int i = blockIdx.x * 4 + wid;
    if (i >= n) return;
    const unsigned beg = rs[i];
    const int deg = (int)(rs[i + 1] - beg);
    const float4* as1v = (const float4*)as1;
    const uint4*  hv4  = (const uint4*)hb;     // row = 20 uint4 (16 GAT + 4 GCN)

    const int e = lane >> 4, c = lane & 15;
    const int h = c >> 2;
    const bool gc = c < 4;

    const float4 dv = ((const float4*)ad1)[i];
    const float dvh = sel4(dv, h);
    const float ni  = nrm[i];

    unsigned pre = (lane < deg) ? csr_src[beg + lane] : (unsigned)i;

    const float4 av = as1v[i];
    const float eself = __expf(leakyf(sel4(av, h) + dvh));

    float acc[8], gacc[8];
#pragma unroll
    for (int t = 0; t < 8; ++t) { acc[t] = 0.f; gacc[t] = 0.f; }
    float sumw = 0.f;

    if (e == 0) {
        uint4 hv = hv4[(size_t)i * 20 + c];
        float2 p0 = unpack2_bf16(hv.x), p1 = unpack2_bf16(hv.y);
        float2 p2 = unpack2_bf16(hv.z), p3 = unpack2_bf16(hv.w);
        acc[0] = p0.x * eself; acc[1] = p0.y * eself;
        acc[2] = p1.x * eself; acc[3] = p1.y * eself;
        acc[4] = p2.x * eself; acc[5] = p2.y * eself;
        acc[6] = p3.x * eself; acc[7] = p3.y * eself;
        if (gc) {
            uint4 gv = hv4[(size_t)i * 20 + 16 + c];
            float w2s = ni * ni;
            float2 q0 = unpack2_bf16(gv.x), q1 = unpack2_bf16(gv.y);
            float2 q2 = unpack2_bf16(gv.z), q3 = unpack2_bf16(gv.w);
            gacc[0] = q0.x * w2s; gacc[1] = q0.y * w2s;
            gacc[2] = q1.x * w2s; gacc[3] = q1.y * w2s;
            gacc[4] = q2.x * w2s; gacc[5] = q2.y * w2s;
            gacc[6] = q3.x * w2s; gacc[7] = q3.y * w2s;
        }
    }

    const int dfast = deg < 64 ? deg : 64;
    const int steps = (dfast + 3) >> 2;

    float4 a_cur = make_float4(0.f, 0.f, 0.f, 0.f);
    uint4  h_cur = make_uint4(0u, 0u, 0u, 0u);
    uint4  g_cur = make_uint4(0u, 0u, 0u, 0u);
    float  nr_cur = 0.f;
    if (steps > 0) {
        unsigned s = __shfl(pre, e, 64);
        if (e >= deg) s = (unsigned)i;
        a_cur = as1v[s];
        h_cur = hv4[(size_t)s * 20 + c];
        if (gc) { g_cur = hv4[(size_t)s * 20 + 16 + c]; nr_cur = nrm[s]; }
    }
    for (int j = 0; j < steps; ++j) {
        float4 a_nxt = a_cur;
        uint4  h_nxt = h_cur, g_nxt = g_cur;
        float  nr_nxt = nr_cur;
        if (j + 1 < steps) {
            int idx = (j + 1) * 4 + e;
            unsigned s = __shfl(pre, idx, 64);
            if (idx >= deg) s = (unsigned)i;
            a_nxt = as1v[s];
            h_nxt = hv4[(size_t)s * 20 + c];
            if (gc) { g_nxt = hv4[(size_t)s * 20 + 16 + c]; nr_nxt = nrm[s]; }
        }
        const bool val = (j * 4 + e) < deg;
        float w = __expf(leakyf(sel4(a_cur, h) + dvh));
        w = val ? w : 0.f;
        sumw += w;
        {
            float2 p0 = unpack2_bf16(h_cur.x), p1 = unpack2_bf16(h_cur.y);
            float2 p2 = unpack2_bf16(h_cur.z), p3 = unpack2_bf16(h_cur.w);
            acc[0] = fmaf(p0.x, w, acc[0]); acc[1] = fmaf(p0.y, w, acc[1]);
            acc[2] = fmaf(p1.x, w, acc[2]); acc[3] = fmaf(p1.y, w, acc[3]);
            acc[4] = fmaf(p2.x, w, acc[4]); acc[5] = fmaf(p2.y, w, acc[5]);
            acc[6] = fmaf(p3.x, w, acc[6]); acc[7] = fmaf(p3.y, w, acc[7]);
        }
        if (gc) {
            float cw = val ? nr_cur * ni : 0.f;
            float2 q0 = unpack2_bf16(g_cur.x), q1 = unpack2_bf16(g_cur.y);
            float2 q2 = unpack2_bf16(g_cur.z), q3 = unpack2_bf16(g_cur.w);
            gacc[0] = fmaf(q0.x, cw, gacc[0]); gacc[1] = fmaf(q0.y, cw, gacc[1]);
            gacc[2] = fmaf(q1.x, cw, gacc[2]); gacc[3] = fmaf(q1.y, cw, gacc[3]);
            gacc[4] = fmaf(q2.x, cw, gacc[4]); gacc[5] = fmaf(q2.y, cw, gacc[5]);
            gacc[6] = fmaf(q3.x, cw, gacc[6]); gacc[7] = fmaf(q3.y, cw, gacc[7]);
        }
        a_cur = a_nxt; h_cur = h_nxt; g_cur = g_nxt; nr_cur = nr_nxt;
    }
    for (int j4 = 64; j4 < deg; j4 += 4) {     // rare tail: deg > 64
        int idx = j4 + e;
        bool val = idx < deg;
        unsigned s = val ? csr_src[beg + idx] : (unsigned)i;
        float4 a = as1v[s];
        float w = val ? __expf(leakyf(sel4(a, h) + dvh)) : 0.f;
        sumw += w;
        uint4 hv = hv4[(size_t)s * 20 + c];
        float2 p0 = unpack2_bf16(hv.x), p1 = unpack2_bf16(hv.y);
        float2 p2 = unpack2_bf16(hv.z), p3 = unpack2_bf16(hv.w);
        acc[0] = fmaf(p0.x, w, acc[0]); acc[1] = fmaf(p0.y, w, acc[1]);
        acc[2] = fmaf(p1.x, w, acc[2]); acc[3] = fmaf(p1.y, w, acc[3]);
        acc[4] = fmaf(p2.x, w, acc[4]); acc[5] = fmaf(p2.y, w, acc[5]);
        acc[6] = fmaf(p3.x, w, acc[6]); acc[7] = fmaf(p3.y, w, acc[7]);
        if (gc) {
            float cw = val ? nrm[s] * ni : 0.f;
            uint4 gv = hv4[(size_t)s * 20 + 16 + c];
            float2 q0 = unpack2_bf16(gv.x), q1 = unpack2_bf16(gv.y);
            float2 q2 = unpack2_bf16(gv.z), q3 = unpack2_bf16(gv.w);
            gacc[0] = fmaf(q0.x, cw, gacc[0]); gacc[1] = fmaf(q0.y, cw, gacc[1]);
            gacc[2] = fmaf(q1.x, cw, gacc[2]); gacc[3] = fmaf(q1.y, cw, gacc[3]);
            gacc[4] = fmaf(q2.x, cw, gacc[4]); gacc[5] = fmaf(q2.y, cw, gacc[5]);
            gacc[6] = fmaf(q3.x, cw, gacc[6]); gacc[7] = fmaf(q3.y, cw, gacc[7]);
        }
    }

#pragma unroll
    for (int t = 0; t < 8; ++t) {
        acc[t]  += __shfl_xor(acc[t], 16, 64);
        acc[t]  += __shfl_xor(acc[t], 32, 64);
        gacc[t] += __shfl_xor(gacc[t], 16, 64);
        gacc[t] += __shfl_xor(gacc[t], 32, 64);
    }
    sumw += __shfl_xor(sumw, 16, 64);
    sumw += __shfl_xor(sumw, 32, 64);
    const float ssh = sumw + eself;

    if (e == 0) {                             // lanes 0-15: final 8ch each
        float inv = 1.f / ssh;
        float4 b0 = *(const float4*)&gat_b1[c * 8];
        float4 b1 = *(const float4*)&gat_b1[c * 8 + 4];
        float o[8] = {acc[0] * inv + b0.x, acc[1] * inv + b0.y,
                      acc[2] * inv + b0.z, acc[3] * inv + b0.w,
                      acc[4] * inv + b1.x, acc[5] * inv + b1.y,
                      acc[6] * inv + b1.z, acc[7] * inv + b1.w};
#pragma unroll
        for (int t = 0; t < 8; ++t) o[t] = o[t] > 0.f ? o[t] : __expf(o[t]) - 1.f;
        uint4 pv = make_uint4(pack2_bf16(o[0], o[1]), pack2_bf16(o[2], o[3]),
                              pack2_bf16(o[4], o[5]), pack2_bf16(o[6], o[7]));
        ((uint4*)xgb)[(size_t)i * 16 + c] = pv;
        if (gc) {                             // lanes 0-3: final gcn 8ch each
            float4 c0 = *(const float4*)&gcn_b1[c * 8];
            float4 c1 = *(const float4*)&gcn_b1[c * 8 + 4];
            float g[8] = {fmaxf(gacc[0] + c0.x, 0.f), fmaxf(gacc[1] + c0.y, 0.f),
                          fmaxf(gacc[2] + c0.z, 0.f), fmaxf(gacc[3] + c0.w, 0.f),
                          fmaxf(gacc[4] + c1.x, 0.f), fmaxf(gacc[5] + c1.y, 0.f),
                          fmaxf(gacc[6] + c1.z, 0.f), fmaxf(gacc[7] + c1.w, 0.f)};
            uint4 gv = make_uint4(pack2_bf16(g[0], g[1]), pack2_bf16(g[2], g[3]),
                                  pack2_bf16(g[4], g[5]), pack2_bf16(g[6], g[7]));
            ((uint4*)gaccb)[(size_t)i * 4 + c] = gv;
        }
    }
}

// ------ fused layer-2 aggregation + head GEMM: 1 node per wave --------------
// R2's agg2 (2-deep pipe, 1 node/wave) + in-wave head. After the quad fold
// (xor 1,2) all 4 lanes of a quad hold the folded chunk sums; cv computed on
// all act lanes. Head: lane oc<40 accumulates over 80 k-steps reading
// Wk[k*41+oc] (LDS, consecutive-oc = conflict-free) with cat[k] broadcast by
// __shfl from the owning quad (compile-time lane index -> readlane).
// Writes d_out directly; removes the head dispatch + 32 MB cat round-trip.
__global__ __launch_bounds__(256) void agg2_fused_kernel(
    const unsigned* __restrict__ hg_b, const float* __restrict__ as2,
    const float* __restrict__ ad2, const float* __restrict__ nrm,
    const unsigned* __restrict__ rs, const unsigned* __restrict__ csr_src,
    const float* __restrict__ gat_b2, const float* __restrict__ gcn_b2,
    const float* __restrict__ wc_p, const float* __restrict__ wt_p,
    const float* __restrict__ lin_W, const float* __restrict__ lin_b,
    float* __restrict__ Y, int n)
{
    __shared__ float Wk[80 * 41];             // Wk[k][oc], stride 41 (conflict-free)
    const int tid = threadIdx.x;
    for (int idx = tid; idx < 3200; idx += 256) {
        int k = idx / 40, oc = idx - k * 40;
        Wk[k * 41 + oc] = lin_W[idx];
    }
    __syncthreads();

    const int wid = tid >> 6;
    const int lane = tid & 63;
    const int i = blockIdx.x * 4 + wid;
    if (i >= n) return;
    const unsigned beg = rs[i];
    const int deg = (int)(rs[i + 1] - beg);
    const int e = lane & 3, c = lane >> 2;
    const bool act = c < 10, isgat = c < 5;
    const float adv = ad2[i];
    const float ni = nrm[i];
    const uint4* hgv = (const uint4*)hg_b;    // row = 10 uint4

    unsigned pre = (lane < deg) ? csr_src[beg + lane] : (unsigned)i;
    const float eself = __expf(leakyf(as2[i] + adv));

    float acc[8];
#pragma unroll
    for (int t = 0; t < 8; ++t) acc[t] = 0.f;
    float sumw = 0.f;

    if (act && e == 0) {                      // self contribution once
        uint4 hv = hgv[(size_t)i * 10 + c];
        float sw = isgat ? eself : ni * ni;
        float2 p0 = unpack2_bf16(hv.x), p1 = unpack2_bf16(hv.y);
        float2 p2 = unpack2_bf16(hv.z), p3 = unpack2_bf16(hv.w);
        acc[0] = p0.x * sw; acc[1] = p0.y * sw;
        acc[2] = p1.x * sw; acc[3] = p1.y * sw;
        acc[4] = p2.x * sw; acc[5] = p2.y * sw;
        acc[6] = p3.x * sw; acc[7] = p3.y * sw;
    }

    const int dfast = deg < 64 ? deg : 64;
    const int steps = (dfast + 3) >> 2;

    float aw_cur = 0.f;
    uint4 h_cur = make_uint4(0u, 0u, 0u, 0u);
    if (steps > 0) {
        unsigned s = __shfl(pre, e, 64);
        if (e >= deg) s = (unsigned)i;
        if (act) { aw_cur = isgat ? as2[s] : nrm[s]; h_cur = hgv[(size_t)s * 10 + c]; }
    }
    for (int j = 0; j < steps; ++j) {
        float aw_nxt = aw_cur;
        uint4 h_nxt = h_cur;
        if (j + 1 < steps) {
            int idx = (j + 1) * 4 + e;
            unsigned s = __shfl(pre, idx, 64);
            if (idx >= deg) s = (unsigned)i;
            if (act) { aw_nxt = isgat ? as2[s] : nrm[s]; h_nxt = hgv[(size_t)s * 10 + c]; }
        }
        const bool val = (j * 4 + e) < deg;
        float w;
        if (isgat) {
            w = __expf(leakyf(aw_cur + adv));
            w = val ? w : 0.f;
            sumw += w;
        } else {
            w = val ? aw_cur * ni : 0.f;
        }
        if (act) {
            float2 p0 = unpack2_bf16(h_cur.x), p1 = unpack2_bf16(h_cur.y);
            float2 p2 = unpack2_bf16(h_cur.z), p3 = unpack2_bf16(h_cur.w);
            acc[0] = fmaf(p0.x, w, acc[0]); acc[1] = fmaf(p0.y, w, acc[1]);
            acc[2] = fmaf(p1.x, w, acc[2]); acc[3] = fmaf(p1.y, w, acc[3]);
            acc[4] = fmaf(p2.x, w, acc[4]); acc[5] = fmaf(p2.y, w, acc[5]);
            acc[6] = fmaf(p3.x, w, acc[6]); acc[7] = fmaf(p3.y, w, acc[7]);
        }
        aw_cur = aw_nxt; h_cur = h_nxt;
    }
    for (int j4 = 64; j4 < deg; j4 += 4) {    // rare tail
        int idx = j4 + e;
        bool val = idx < deg;
        unsigned s = val ? csr_src[beg + idx] : (unsigned)i;
        if (act) {
            float aw = isgat ? as2[s] : nrm[s];
            float w;
            if (isgat) {
                w = val ? __expf(leakyf(aw + adv)) : 0.f;
                sumw += w;
            } else {
                w = val ? aw * ni : 0.f;
            }
            uint4 hv = hgv[(size_t)s * 10 + c];
            float2 p0 = unpack2_bf16(hv.x), p1 = unpack2_bf16(hv.y);
            float2 p2 = unpack2_bf16(hv.z), p3 = unpack2_bf16(hv.w);
            acc[0] = fmaf(p0.x, w, acc[0]); acc[1] = fmaf(p0.y, w, acc[1]);
            acc[2] = fmaf(p1.x, w, acc[2]); acc[3] = fmaf(p1.y, w, acc[3]);
            acc[4] = fmaf(p2.x, w, acc[4]); acc[5] = fmaf(p2.y, w, acc[5]);
            acc[6] = fmaf(p3.x, w, acc[6]); acc[7] = fmaf(p3.y, w, acc[7]);
        }
    }

    // quad fold: all 4 lanes of each chunk hold the totals afterwards
#pragma unroll
    for (int t = 0; t < 8; ++t) {
        acc[t] += __shfl_xor(acc[t], 1, 64);
        acc[t] += __shfl_xor(acc[t], 2, 64);
    }
    sumw += __shfl_xor(sumw, 1, 64);
    sumw += __shfl_xor(sumw, 2, 64);
    const float ssum = sumw + eself;

    // per-lane cat chunk (8 values) on every act lane
    float cv[8];
#pragma unroll
    for (int t = 0; t < 8; ++t) cv[t] = 0.f;
    if (isgat) {
        float inv = 1.f / ssum, wt = *wt_p;
        float4 b0 = *(const float4*)&gat_b2[c * 8];
        float4 b1 = *(const float4*)&gat_b2[c * 8 + 4];
        float bb[8] = {b0.x, b0.y, b0.z, b0.w, b1.x, b1.y, b1.z, b1.w};
#pragma unroll
        for (int t = 0; t < 8; ++t) cv[t] = (acc[t] * inv + bb[t]) * wt;
    } else if (act) {
        float wc = *wc_p;
        float4 b0 = *(const float4*)&gcn_b2[(c - 5) * 8];
        float4 b1 = *(const float4*)&gcn_b2[(c - 5) * 8 + 4];
        float bb[8] = {b0.x, b0.y, b0.z, b0.w, b1.x, b1.y, b1.z, b1.w};
#pragma unroll
        for (int t = 0; t < 8; ++t) cv[t] = (acc[t] + bb[t]) * wc;
    }

    // head: out[oc] = lin_b[oc] + sum_k cat[k] * lin_W[k][oc]
    // cat order: k<40 = gcn (chunk 5+k/8), k>=40 = gat (chunk k/8-5)
    const int oc = lane < 40 ? lane : 0;
    float o = lin_b[oc];
#pragma unroll
    for (int kc = 0; kc < 10; ++kc) {
        const int srcl = 4 * (kc < 5 ? 5 + kc : kc - 5);
#pragma unroll
        for (int t = 0; t < 8; ++t) {
            float ca = __shfl(cv[t], srcl, 64);
            o = fmaf(ca, Wk[(kc * 8 + t) * 41 + oc], o);
        }
    }
    if (lane < 40) Y[(size_t)i * 40 + lane] = o;
}

// ---------------- host ------------------------------------------------------
extern "C" void kernel_launch(void* const* d_in, const int* in_sizes, int n_in,
                              void* d_out, int out_size, void* d_ws, size_t ws_size,
                              hipStream_t stream)
{
    const float* x        = (const float*)d_in[0];
    const int*   eidx     = (const int*)d_in[1];
    const float* gat_W1   = (const float*)d_in[2];
    const float* att_s1   = (const float*)d_in[3];
    const float* att_d1   = (const float*)d_in[4];
    const float* gat_b1   = (const float*)d_in[5];
    const float* gat_W2   = (const float*)d_in[6];
    const float* att_s2   = (const float*)d_in[7];
    const float* att_d2   = (const float*)d_in[8];
    const float* gat_b2   = (const float*)d_in[9];
    const float* gcn_W1   = (const float*)d_in[10];
    const float* gcn_b1   = (const float*)d_in[11];
    const float* gcn_W2   = (const float*)d_in[12];
    const float* gcn_b2   = (const float*)d_in[13];
    const float* lin_W    = (const float*)d_in[14];
    const float* lin_b    = (const float*)d_in[15];
    const float* wc_p     = (const float*)d_in[16];
    const float* wt_p     = (const float*)d_in[17];

    const int n = in_sizes[0] / F_IN;      // 50000
    const int e = in_sizes[1] / 2;         // 800000
    const int* src = eidx;
    const int* dst = eidx + e;
    const int NBUCK = (n + 127) >> 7;      // 391

    char* p = (char*)d_ws;
    auto alloc = [&](size_t bytes) -> void* {
        void* r = (void*)p;
        p += (bytes + 255) & ~(size_t)255;
        return r;
    };
    unsigned* counts  = (unsigned*)alloc((size_t)n * 4);
    unsigned* rs      = (unsigned*)alloc((size_t)(n + 1) * 4);
    unsigned* cursor  = (unsigned*)alloc((size_t)n * 4);
    unsigned* partials= (unsigned*)alloc(256 * 4);
    unsigned* bcnt    = (unsigned*)alloc((size_t)(NBUCK + 1) * 4);
    unsigned* csr_src = (unsigned*)alloc((size_t)e * 4);
    uint4*    wbf     = (uint4*)alloc(40 * 64 * 16);
    float* nrm     = (float*)alloc((size_t)n * 4);
    float* as1     = (float*)alloc((size_t)n * 4 * 4);
    float* ad1     = (float*)alloc((size_t)n * 4 * 4);
    float* as2     = (float*)alloc((size_t)n * 4);
    float* ad2     = (float*)alloc((size_t)n * 4);
    unsigned* hb   = (unsigned*)alloc((size_t)n * 80 * 4); // h1 staging; earlier: bpair/ovf
    unsigned* hg_b = (unsigned*)alloc((size_t)n * 40 * 4);
    float* xg      = (float*)alloc((size_t)n * F_IN * 4); // xgb bf16
    unsigned* gaccb= (unsigned*)alloc((size_t)n * 16 * 4);
    // aliases with disjoint lifetimes (stream-ordered):
    unsigned* bpair = hb;
    uint2*    ovf   = (uint2*)(bpair + (size_t)NBUCK * BCAP);
    unsigned* xgb   = (unsigned*)xg;
    unsigned* ovf_cnt = bcnt + NBUCK;

    const int NB = (n + 255) / 256;
    const int WB = (n + 3) / 4;
    const int SB = (e + SCHUNK - 1) / SCHUNK;

    // ---- W pre-pack (also zeroes bcnt, replacing the memset dispatch) ----
    wb_prep_kernel<<<40, 64, 0, stream>>>(gat_W1, gcn_W1, wbf, bcnt, NBUCK + 1);

    // ---- CSR build ----
    bucket_scatter_kernel<<<SB, 256, 0, stream>>>(src, dst, bcnt, bpair, ovf_cnt, ovf, e, NBUCK);
    bucket_count_kernel<<<NBUCK, 256, 0, stream>>>(bcnt, bpair, ovf_cnt, ovf, counts, n);
    scan_reduce_kernel<<<NB, 256, 0, stream>>>(counts, partials, n);
    scan_partials_kernel<<<1, 256, 0, stream>>>(partials, rs, NB, n);
    scan_write_kernel<<<NB, 256, 0, stream>>>(counts, partials, rs, nrm, n);
    bucket_place_kernel<<<NBUCK, 256, 0, stream>>>(bcnt, bpair, rs, csr_src, cursor, n);
    overflow_fill_kernel<<<1, 256, 0, stream>>>(ovf_cnt, ovf, cursor, csr_src);

    // ---- MFMA first-layer GEMM (fused logits1) ----
    gemm1_mfma_kernel<<<(n + 63) / 64, 256, 0, stream>>>(x, wbf, att_s1, att_d1,
                                                         hb, as1, ad1, n);

    // ---- fused layer-1 aggregation (single-pass GAT softmax + GCN norm) ----
    agg1_fused_kernel<<<WB, 256, 0, stream>>>(hb, as1, ad1, nrm, rs, csr_src,
                                              gat_b1, gcn_b1, xgb, gaccb, n);

    // ---- layer-2 GEMMs into hg_b (gat gemm fuses logits2) ----
    gemm_tile_bb<32, 40, 128, 32, 40, 20><<<(n + 127) / 128, 320, 0, stream>>>(gaccb, gcn_W2, hg_b, n);
    gemm2_gat_kernel<<<(n + 127) / 128, 320, 0, stream>>>(xgb, gat_W2, att_s2, att_d2,
                                                          hg_b, as2, ad2, n);

    // ---- fused layer-2 aggregation + head -> d_out ----
    agg2_fused_kernel<<<WB, 256, 0, stream>>>(hg_b, as2, ad2, nrm, rs, csr_src,
                                              gat_b2, gcn_b2, wc_p, wt_p,
                                              lin_W, lin_b, (float*)d_out, n);
}

// Round 6
// 300.898 us; speedup vs baseline: 1.2388x; 1.2388x over previous
//
#include <hip/hip_runtime.h>
#include <math.h>

#define F_IN   128
#define HIDC   32
#define NHEAD  4
#define CDIM   40
#define NEG_SLOPE 0.2f
#define BCAP   4096
#define OVCAP  16384
#define SCHUNK 4096

typedef __attribute__((ext_vector_type(8))) short bf16x8;   // 8 bf16 = 4 VGPRs
typedef __attribute__((ext_vector_type(4))) float f32x4;    // MFMA C/D

__device__ __forceinline__ float leakyf(float x) { return x > 0.f ? x : NEG_SLOPE * x; }

__device__ __forceinline__ float sel4(float4 v, int h) {
    return (h == 0) ? v.x : (h == 1) ? v.y : (h == 2) ? v.z : v.w;
}
__device__ __forceinline__ unsigned pack2_bf16(float a, float b) {
    unsigned ua = __float_as_uint(a);
    unsigned ub = __float_as_uint(b);
    ua = (ua + 0x7FFFu + ((ua >> 16) & 1u)) >> 16;
    ub = (ub + 0x7FFFu + ((ub >> 16) & 1u)) >> 16;
    return ua | (ub << 16);
}
__device__ __forceinline__ float2 unpack2_bf16(unsigned p) {
    return make_float2(__uint_as_float(p << 16), __uint_as_float(p & 0xFFFF0000u));
}

// ---- W pre-pack into MFMA B-fragment order + bcnt/partials zeroing --------
__global__ void wb_prep_kernel(const float* __restrict__ Wg, const float* __restrict__ Wc,
                               uint4* __restrict__ wbf, unsigned* __restrict__ bcnt,
                               int nbuck1, unsigned* __restrict__ partials)
{
    int b = blockIdx.x;            // nt*4 + ks, 0..39
    int lane = threadIdx.x;        // 0..63
    int gtid = b * 64 + lane;
    if (gtid < nbuck1) bcnt[gtid] = 0u;
    if (gtid < 256) partials[gtid] = 0u;
    int nt = b >> 2, ks = b & 3;
    int c = nt * 16 + (lane & 15);
    int k0 = ks * 32 + (lane >> 4) * 8;
    unsigned u[4];
#pragma unroll
    for (int jj = 0; jj < 4; ++jj) {
        int k = k0 + 2 * jj;
        float a0 = (c < 128) ? Wg[(size_t)k * 128 + c] : Wc[(size_t)k * 32 + (c - 128)];
        float a1 = (c < 128) ? Wg[(size_t)(k + 1) * 128 + c] : Wc[(size_t)(k + 1) * 32 + (c - 128)];
        u[jj] = pack2_bf16(a0, a1);
    }
    wbf[(size_t)b * 64 + lane] = make_uint4(u[0], u[1], u[2], u[3]);
}

// ---- first-layer GEMM on MFMA + fused logits1 epilogue --------------------
// Output row layout: hb[node][80] unsigned = 64 GAT (128ch bf16) + 16 GCN (32ch bf16)
__global__ __launch_bounds__(256) void gemm1_mfma_kernel(
    const float* __restrict__ X, const uint4* __restrict__ wbf,
    const float* __restrict__ aw_s, const float* __restrict__ aw_d,
    unsigned* __restrict__ hb,
    float* __restrict__ as1, float* __restrict__ ad1, int n)
{
    __shared__ float Ct[64][164];
    __shared__ float sw[128], dw[128];
    const int tid = threadIdx.x;
    const int w = tid >> 6, lane = tid & 63;
    const int m = lane & 15, q = lane >> 4;
    const int node0 = blockIdx.x * 64;
    if (tid < 128) { sw[tid] = aw_s[tid]; dw[tid] = aw_d[tid]; }

    f32x4 acc[10];
#pragma unroll
    for (int t = 0; t < 10; ++t) acc[t] = (f32x4){0.f, 0.f, 0.f, 0.f};

    const int row = node0 + w * 16 + m;
    const bool rv = row < n;
#pragma unroll
    for (int ks = 0; ks < 4; ++ks) {
        uint4 pa = make_uint4(0u, 0u, 0u, 0u);
        if (rv) {
            const float* xr = X + (size_t)row * 128 + ks * 32 + q * 8;
            float4 a0 = *(const float4*)xr;
            float4 a1 = *(const float4*)(xr + 4);
            pa = make_uint4(pack2_bf16(a0.x, a0.y), pack2_bf16(a0.z, a0.w),
                            pack2_bf16(a1.x, a1.y), pack2_bf16(a1.z, a1.w));
        }
        bf16x8 af = *(bf16x8*)&pa;
#pragma unroll
        for (int nt = 0; nt < 10; ++nt) {
            uint4 pb = wbf[(size_t)(nt * 4 + ks) * 64 + lane];
            bf16x8 bfv = *(bf16x8*)&pb;
            acc[nt] = __builtin_amdgcn_mfma_f32_16x16x32_bf16(af, bfv, acc[nt], 0, 0, 0);
        }
    }
#pragma unroll
    for (int nt = 0; nt < 10; ++nt)
#pragma unroll
        for (int r = 0; r < 4; ++r)
            Ct[w * 16 + q * 4 + r][nt * 16 + m] = acc[nt][r];
    __syncthreads();

    for (int i = tid; i < 64 * 64; i += 256) {
        int nd = i >> 6, u = i & 63;
        int gn = node0 + nd;
        if (gn < n)
            hb[(size_t)gn * 80 + u] = pack2_bf16(Ct[nd][2 * u], Ct[nd][2 * u + 1]);
    }
    for (int i = tid; i < 64 * 16; i += 256) {
        int nd = i >> 4, u = i & 15;
        int gn = node0 + nd;
        if (gn < n)
            hb[(size_t)gn * 80 + 64 + u] = pack2_bf16(Ct[nd][128 + 2 * u], Ct[nd][128 + 2 * u + 1]);
    }
    {
        int nd = tid >> 2, h = tid & 3;
        int gn = node0 + nd;
        if (gn < n) {
            float s = 0.f, d = 0.f;
#pragma unroll
            for (int k = 0; k < HIDC; ++k) {
                float v = Ct[nd][h * HIDC + k];
                s = fmaf(v, sw[h * HIDC + k], s);
                d = fmaf(v, dw[h * HIDC + k], d);
            }
            as1[(size_t)gn * 4 + h] = s;
            ad1[(size_t)gn * 4 + h] = d;
        }
    }
}

// ---------------- tiled GEMM (fp32 in/out, head) ----------------------------
template<int K, int OUTC, int BN, int BK, int OSTRIDE = OUTC>
__global__ __launch_bounds__((OUTC / 4) * (BN / 4)) void gemm_tile(
    const float* __restrict__ X, const float* __restrict__ W,
    const float* __restrict__ bias, float* __restrict__ Y, int n)
{
    constexpr int CG = OUTC / 4;
    constexpr int NG = BN / 4;
    constexpr int NT = CG * NG;
    __shared__ float Xs[BK][BN + 4];
    __shared__ float Ws[BK][OUTC];
    const int tid = threadIdx.x;
    const int cg = tid % CG, ng = tid / CG;
    const int node0 = blockIdx.x * BN;
    float acc[4][4] = {};

    for (int kb = 0; kb < K; kb += BK) {
        for (int idx = tid; idx < BN * (BK / 4); idx += NT) {
            int nd = idx / (BK / 4);
            int kq = idx % (BK / 4);
            int gnode = node0 + nd;
            float4 v = (gnode < n) ? *(const float4*)&X[(size_t)gnode * K + kb + kq * 4]
                                   : make_float4(0.f, 0.f, 0.f, 0.f);
            Xs[kq * 4 + 0][nd] = v.x;
            Xs[kq * 4 + 1][nd] = v.y;
            Xs[kq * 4 + 2][nd] = v.z;
            Xs[kq * 4 + 3][nd] = v.w;
        }
        for (int idx = tid; idx < BK * CG; idx += NT) {
            int kk = idx / CG;
            int cq = idx % CG;
            *(float4*)&Ws[kk][cq * 4] = *(const float4*)&W[(size_t)(kb + kk) * OUTC + cq * 4];
        }
        __syncthreads();
#pragma unroll
        for (int k = 0; k < BK; ++k) {
            float4 xv = *(const float4*)&Xs[k][ng * 4];
            float4 wv = *(const float4*)&Ws[k][cg * 4];
            float xa[4] = {xv.x, xv.y, xv.z, xv.w};
            float wa[4] = {wv.x, wv.y, wv.z, wv.w};
#pragma unroll
            for (int j = 0; j < 4; ++j)
#pragma unroll
                for (int c = 0; c < 4; ++c)
                    acc[j][c] = fmaf(xa[j], wa[c], acc[j][c]);
        }
        __syncthreads();
    }

    float4 bv = make_float4(0.f, 0.f, 0.f, 0.f);
    if (bias) bv = *(const float4*)&bias[cg * 4];
#pragma unroll
    for (int j = 0; j < 4; ++j) {
        int gnode = node0 + ng * 4 + j;
        if (gnode < n) {
            float4 o = make_float4(acc[j][0] + bv.x, acc[j][1] + bv.y,
                                   acc[j][2] + bv.z, acc[j][3] + bv.w);
            *(float4*)&Y[(size_t)gnode * OSTRIDE + cg * 4] = o;
        }
    }
}

// bf16-in (packed), bf16-out variant (gcn L2 gemm)
template<int K, int OUTC, int BN, int BK, int OSTRIDE_U, int OFF_U>
__global__ __launch_bounds__((OUTC / 4) * (BN / 4)) void gemm_tile_bb(
    const unsigned* __restrict__ Xb, const float* __restrict__ W,
    unsigned* __restrict__ Yb, int n)
{
    constexpr int CG = OUTC / 4;
    constexpr int NG = BN / 4;
    constexpr int NT = CG * NG;
    __shared__ float Xs[BK][BN + 4];
    __shared__ float Ws[BK][OUTC];
    const int tid = threadIdx.x;
    const int cg = tid % CG, ng = tid / CG;
    const int node0 = blockIdx.x * BN;
    float acc[4][4] = {};

    for (int kb = 0; kb < K; kb += BK) {
        for (int idx = tid; idx < BN * (BK / 8); idx += NT) {
            int nd = idx / (BK / 8);
            int kq = idx % (BK / 8);
            int gnode = node0 + nd;
            uint4 v = (gnode < n) ? *(const uint4*)&Xb[(size_t)gnode * (K / 2) + kb / 2 + kq * 4]
                                  : make_uint4(0u, 0u, 0u, 0u);
            float2 a = unpack2_bf16(v.x), b = unpack2_bf16(v.y);
            float2 c = unpack2_bf16(v.z), d = unpack2_bf16(v.w);
            Xs[kq * 8 + 0][nd] = a.x; Xs[kq * 8 + 1][nd] = a.y;
            Xs[kq * 8 + 2][nd] = b.x; Xs[kq * 8 + 3][nd] = b.y;
            Xs[kq * 8 + 4][nd] = c.x; Xs[kq * 8 + 5][nd] = c.y;
            Xs[kq * 8 + 6][nd] = d.x; Xs[kq * 8 + 7][nd] = d.y;
        }
        for (int idx = tid; idx < BK * CG; idx += NT) {
            int kk = idx / CG;
            int cq = idx % CG;
            *(float4*)&Ws[kk][cq * 4] = *(const float4*)&W[(size_t)(kb + kk) * OUTC + cq * 4];
        }
        __syncthreads();
#pragma unroll
        for (int k = 0; k < BK; ++k) {
            float4 xv = *(const float4*)&Xs[k][ng * 4];
            float4 wv = *(const float4*)&Ws[k][cg * 4];
            float xa[4] = {xv.x, xv.y, xv.z, xv.w};
            float wa[4] = {wv.x, wv.y, wv.z, wv.w};
#pragma unroll
            for (int j = 0; j < 4; ++j)
#pragma unroll
                for (int c = 0; c < 4; ++c)
                    acc[j][c] = fmaf(xa[j], wa[c], acc[j][c]);
        }
        __syncthreads();
    }

#pragma unroll
    for (int j = 0; j < 4; ++j) {
        int gnode = node0 + ng * 4 + j;
        if (gnode < n) {
            uint2 pb = make_uint2(pack2_bf16(acc[j][0], acc[j][1]),
                                  pack2_bf16(acc[j][2], acc[j][3]));
            *(uint2*)&Yb[(size_t)gnode * OSTRIDE_U + OFF_U + cg * 2] = pb;
        }
    }
}

// ---- GAT L2 GEMM (bf16 in/out) + fused logits2 epilogue --------------------
__global__ __launch_bounds__(320) void gemm2_gat_kernel(
    const unsigned* __restrict__ Xb, const float* __restrict__ W,
    const float* __restrict__ aw_s, const float* __restrict__ aw_d,
    unsigned* __restrict__ Yb, float* __restrict__ as2, float* __restrict__ ad2, int n)
{
    constexpr int K = 128, OUTC = 40, BN = 128, BK = 32;
    constexpr int CG = OUTC / 4, NT = 320;
    __shared__ float smem[32 * 132 + 32 * 40];     // 5504 floats
    float* Xs = smem;                               // [32][132]
    float* Ws = smem + 32 * 132;                    // [32][40]
    const int tid = threadIdx.x;
    const int cg = tid % CG, ng = tid / CG;
    const int node0 = blockIdx.x * BN;
    float acc[4][4] = {};

    for (int kb = 0; kb < K; kb += BK) {
        for (int idx = tid; idx < BN * (BK / 8); idx += NT) {
            int nd = idx / (BK / 8);
            int kq = idx % (BK / 8);
            int gnode = node0 + nd;
            uint4 v = (gnode < n) ? *(const uint4*)&Xb[(size_t)gnode * (K / 2) + kb / 2 + kq * 4]
                                  : make_uint4(0u, 0u, 0u, 0u);
            float2 a = unpack2_bf16(v.x), b = unpack2_bf16(v.y);
            float2 c = unpack2_bf16(v.z), d = unpack2_bf16(v.w);
            Xs[(kq * 8 + 0) * 132 + nd] = a.x; Xs[(kq * 8 + 1) * 132 + nd] = a.y;
            Xs[(kq * 8 + 2) * 132 + nd] = b.x; Xs[(kq * 8 + 3) * 132 + nd] = b.y;
            Xs[(kq * 8 + 4) * 132 + nd] = c.x; Xs[(kq * 8 + 5) * 132 + nd] = c.y;
            Xs[(kq * 8 + 6) * 132 + nd] = d.x; Xs[(kq * 8 + 7) * 132 + nd] = d.y;
        }
        for (int idx = tid; idx < BK * CG; idx += NT) {
            int kk = idx / CG;
            int cq = idx % CG;
            *(float4*)&Ws[kk * 40 + cq * 4] = *(const float4*)&W[(size_t)(kb + kk) * OUTC + cq * 4];
        }
        __syncthreads();
#pragma unroll
        for (int k = 0; k < BK; ++k) {
            float4 xv = *(const float4*)&Xs[k * 132 + ng * 4];
            float4 wv = *(const float4*)&Ws[k * 40 + cg * 4];
            float xa[4] = {xv.x, xv.y, xv.z, xv.w};
            float wa[4] = {wv.x, wv.y, wv.z, wv.w};
#pragma unroll
            for (int j = 0; j < 4; ++j)
#pragma unroll
                for (int c = 0; c < 4; ++c)
                    acc[j][c] = fmaf(xa[j], wa[c], acc[j][c]);
        }
        __syncthreads();
    }

    // global bf16 write + stage Ct for logits
    float* Ct  = smem;              // [128][41]
    float* sww = smem + 128 * 41;   // [40]
    float* dww = sww + 40;          // [40]
#pragma unroll
    for (int j = 0; j < 4; ++j) {
        int gnode = node0 + ng * 4 + j;
        if (gnode < n) {
            uint2 pb = make_uint2(pack2_bf16(acc[j][0], acc[j][1]),
                                  pack2_bf16(acc[j][2], acc[j][3]));
            *(uint2*)&Yb[(size_t)gnode * 40 + cg * 2] = pb;
        }
#pragma unroll
        for (int c = 0; c < 4; ++c)
            Ct[(ng * 4 + j) * 41 + cg * 4 + c] = acc[j][c];
    }
    if (tid < 40) { sww[tid] = aw_s[tid]; dww[tid] = aw_d[tid]; }
    __syncthreads();
    if (tid < 128) {
        int gnode = node0 + tid;
        if (gnode < n) {
            float s = 0.f, d = 0.f;
#pragma unroll
            for (int c = 0; c < 40; ++c) {
                float v = Ct[tid * 41 + c];
                s = fmaf(v, sww[c], s);
                d = fmaf(v, dww[c], d);
            }
            as2[gnode] = s;
            ad2[gnode] = d;
        }
    }
}

// ---------------- CSR build: bucketed counting sort by dst ------------------
__global__ __launch_bounds__(256) void bucket_scatter_kernel(
    const int* __restrict__ src, const int* __restrict__ dst,
    unsigned* __restrict__ bcnt, unsigned* __restrict__ bpair,
    unsigned* __restrict__ ovf_cnt, uint2* __restrict__ ovf, int e, int nbuck)
{
    __shared__ unsigned hist[512];
    __shared__ unsigned base[512];
    const int t = threadIdx.x;
    const int lo = blockIdx.x * SCHUNK;
    const int hi = min(lo + SCHUNK, e);
    for (int i = t; i < nbuck; i += 256) hist[i] = 0;
    __syncthreads();
    for (int i = lo + t; i < hi; i += 256)
        atomicAdd(&hist[((unsigned)dst[i]) >> 7], 1u);
    __syncthreads();
    for (int i = t; i < nbuck; i += 256) {
        unsigned c = hist[i];
        base[i] = c ? atomicAdd(&bcnt[i], c) : 0u;
        hist[i] = 0;
    }
    __syncthreads();
    for (int i = lo + t; i < hi; i += 256) {
        unsigned s = (unsigned)src[i], d = (unsigned)dst[i];
        unsigned b = d >> 7;
        unsigned pos = base[b] + atomicAdd(&hist[b], 1u);
        if (pos < BCAP) bpair[(size_t)b * BCAP + pos] = s | ((d & 127u) << 16);
        else {
            unsigned o = atomicAdd(ovf_cnt, 1u);
            if (o < OVCAP) ovf[o] = make_uint2(s, d);
        }
    }
}

// counts per node + per-scan-block partial sums (replaces scan_reduce pass;
// partials zeroed in wb_prep, scan-block sb = bucket b >> 1)
__global__ __launch_bounds__(256) void bucket_count_kernel(
    const unsigned* __restrict__ bcnt, const unsigned* __restrict__ bpair,
    const unsigned* __restrict__ ovf_cnt, const uint2* __restrict__ ovf,
    unsigned* __restrict__ counts, unsigned* __restrict__ partials, int n)
{
    __shared__ unsigned lc[128];
    const int b = blockIdx.x, base = b << 7;
    if (threadIdx.x < 128) lc[threadIdx.x] = 0;
    __syncthreads();
    unsigned bc = bcnt[b];
    int cnt = (int)(bc < BCAP ? bc : BCAP);
    for (int k = threadIdx.x; k < cnt; k += 256)
        atomicAdd(&lc[bpair[(size_t)b * BCAP + k] >> 16], 1u);
    unsigned oc_u = *ovf_cnt;
    int oc = (int)(oc_u < OVCAP ? oc_u : OVCAP);
    for (int k = threadIdx.x; k < oc; k += 256) {
        uint2 pp = ovf[k];
        if ((int)(pp.y >> 7) == b) atomicAdd(&lc[pp.y & 127u], 1u);
    }
    __syncthreads();
    int i = base + threadIdx.x;
    if (threadIdx.x < 128 && i < n) counts[i] = lc[threadIdx.x];
    __syncthreads();
#pragma unroll
    for (int off = 64; off > 0; off >>= 1) {
        if (threadIdx.x < off) lc[threadIdx.x] += lc[threadIdx.x + off];
        __syncthreads();
    }
    if (threadIdx.x == 0 && lc[0]) atomicAdd(&partials[b >> 1], lc[0]);
}

__global__ __launch_bounds__(256) void scan_partials_kernel(unsigned* __restrict__ partials,
                                                            unsigned* __restrict__ rs, int nb, int n)
{
    __shared__ unsigned sm[256];
    int t = threadIdx.x;
    unsigned v = (t < nb) ? partials[t] : 0u;
    sm[t] = v;
    __syncthreads();
#pragma unroll
    for (int off = 1; off < 256; off <<= 1) {
        unsigned u = (t >= off) ? sm[t - off] : 0u;
        __syncthreads();
        sm[t] += u;
        __syncthreads();
    }
    if (t < nb) partials[t] = sm[t] - v;
    if (t == 255) rs[n] = sm[255];
}

__global__ __launch_bounds__(256) void scan_write_kernel(const unsigned* __restrict__ counts,
                                                         const unsigned* __restrict__ partials,
                                                         unsigned* __restrict__ rs,
                                                         float* __restrict__ nrm, int n)
{
    __shared__ unsigned sm[256];
    int t = threadIdx.x;
    int i = blockIdx.x * 256 + t;
    unsigned c = (i < n) ? counts[i] : 0u;
    sm[t] = c;
    __syncthreads();
#pragma unroll
    for (int off = 1; off < 256; off <<= 1) {
        unsigned u = (t >= off) ? sm[t - off] : 0u;
        __syncthreads();
        sm[t] += u;
        __syncthreads();
    }
    if (i < n) {
        rs[i] = partials[blockIdx.x] + sm[t] - c;
        nrm[i] = rsqrtf((float)(c + 1u));
    }
}

__global__ __launch_bounds__(256) void bucket_place_kernel(
    const unsigned* __restrict__ bcnt, const unsigned* __restrict__ bpair,
    const unsigned* __restrict__ rs, unsigned* __restrict__ csr_src,
    unsigned* __restrict__ cursor, int n)
{
    __shared__ unsigned lc[128];
    __shared__ unsigned rbase[128];
    const int b = blockIdx.x, base = b << 7;
    if (threadIdx.x < 128) {
        lc[threadIdx.x] = 0;
        int i = base + threadIdx.x;
        rbase[threadIdx.x] = (i < n) ? rs[i] : 0u;
    }
    __syncthreads();
    unsigned bc = bcnt[b];
    int cnt = (int)(bc < BCAP ? bc : BCAP);
    for (int k = threadIdx.x; k < cnt; k += 256) {
        unsigned v = bpair[(size_t)b * BCAP + k];
        unsigned ld = v >> 16;
        unsigned r = atomicAdd(&lc[ld], 1u);
        csr_src[rbase[ld] + r] = v & 0xFFFFu;
    }
    __syncthreads();
    int i = base + threadIdx.x;
    if (threadIdx.x < 128 && i < n) cursor[i] = rbase[threadIdx.x] + lc[threadIdx.x];
}

__global__ void overflow_fill_kernel(const unsigned* __restrict__ ovf_cnt,
                                     const uint2* __restrict__ ovf,
                                     unsigned* __restrict__ cursor,
                                     unsigned* __restrict__ csr_src)
{
    unsigned oc_u = *ovf_cnt;
    int oc = (int)(oc_u < OVCAP ? oc_u : OVCAP);
    for (int k = threadIdx.x; k < oc; k += 256) {
        uint2 pp = ovf[k];
        unsigned pos = atomicAdd(&cursor[pp.y], 1u);
        csr_src[pos] = pp.x;
    }
}

// -------- fused layer-1 aggregation: single-pass, LDS-free (R2 config) ------
// One wave per node, 2-deep pipeline (8 edges in flight), 36 VGPR / ~62% occ.
// Sits at the measured random-gather latency/BW floor (~2.6 TB/s L2-miss on
// ~146 MB); LDS staging, 2-node, deeper pipes, epilogue fusion all regress.
__global__ __launch_bounds__(256) void agg1_fused_kernel(
    const unsigned* __restrict__ hb,
    const float* __restrict__ as1, const float* __restrict__ ad1,
    const float* __restrict__ nrm,
    const unsigned* __restrict__ rs, const unsigned* __restrict__ csr_src,
    const float* __restrict__ gat_b1, const float* __restrict__ gcn_b1,
    unsigned* __restrict__ xgb, unsigned* __restrict__ gaccb, int n)
{
    const int wid = threadIdx.x >> 6;
    const int lane = threadIdx.x & 63;
    const int i = blockIdx.x * 4 + wid;
    if (i >= n) return;
    const unsigned beg = rs[i];
    const int deg = (int)(rs[i + 1] - beg);
    const float4* as1v = (const float4*)as1;
    const uint4*  hv4  = (const uint4*)hb;     // row = 20 uint4 (16 GAT + 4 GCN)

    const int e = lane >> 4, c = lane & 15;
    const int h = c >> 2;
    const bool gc = c < 4;

    const float4 dv = ((const float4*)ad1)[i];
    const float dvh = sel4(dv, h);
    const float ni  = nrm[i];

    unsigned pre = (lane < deg) ? csr_src[beg + lane] : (unsigned)i;

    const float4 av = as1v[i];
    const float eself = __expf(leakyf(sel4(av, h) + dvh));

    float acc[8], gacc[8];
#pragma unroll
    for (int t = 0; t < 8; ++t) { acc[t] = 0.f; gacc[t] = 0.f; }
    float sumw = 0.f;

    if (e == 0) {
        uint4 hv = hv4[(size_t)i * 20 + c];
        float2 p0 = unpack2_bf16(hv.x), p1 = unpack2_bf16(hv.y);
        float2 p2 = unpack2_bf16(hv.z), p3 = unpack2_bf16(hv.w);
        acc[0] = p0.x * eself; acc[1] = p0.y * eself;
        acc[2] = p1.x * eself; acc[3] = p1.y * eself;
        acc[4] = p2.x * eself; acc[5] = p2.y * eself;
        acc[6] = p3.x * eself; acc[7] = p3.y * eself;
        if (gc) {
            uint4 gv = hv4[(size_t)i * 20 + 16 + c];
            float w2s = ni * ni;
            float2 q0 = unpack2_bf16(gv.x), q1 = unpack2_bf16(gv.y);
            float2 q2 = unpack2_bf16(gv.z), q3 = unpack2_bf16(gv.w);
            gacc[0] = q0.x * w2s; gacc[1] = q0.y * w2s;
            gacc[2] = q1.x * w2s; gacc[3] = q1.y * w2s;
            gacc[4] = q2.x * w2s; gacc[5] = q2.y * w2s;
            gacc[6] = q3.x * w2s; gacc[7] = q3.y * w2s;
        }
    }

    const int dfast = deg < 64 ? deg : 64;
    const int steps = (dfast + 3) >> 2;

    float4 a_cur = make_float4(0.f, 0.f, 0.f, 0.f);
    uint4  h_cur = make_uint4(0u, 0u, 0u, 0u);
    uint4  g_cur = make_uint4(0u, 0u, 0u, 0u);
    float  nr_cur = 0.f;
    if (steps > 0) {
        unsigned s = __shfl(pre, e, 64);
        if (e >= deg) s = (unsigned)i;
        a_cur = as1v[s];
        h_cur = hv4[(size_t)s * 20 + c];
        if (gc) { g_cur = hv4[(size_t)s * 20 + 16 + c]; nr_cur = nrm[s]; }
    }
    for (int j = 0; j < steps; ++j) {
        float4 a_nxt = a_cur;
        uint4  h_nxt = h_cur, g_nxt = g_cur;
        float  nr_nxt = nr_cur;
        if (j + 1 < steps) {
            int idx = (j + 1) * 4 + e;
            unsigned s = __shfl(pre, idx, 64);
            if (idx >= deg) s = (unsigned)i;
            a_nxt = as1v[s];
            h_nxt = hv4[(size_t)s * 20 + c];
            if (gc) { g_nxt = hv4[(size_t)s * 20 + 16 + c]; nr_nxt = nrm[s]; }
        }
        const bool val = (j * 4 + e) < deg;
        float w = __expf(leakyf(sel4(a_cur, h) + dvh));
        w = val ? w : 0.f;
        sumw += w;
        {
            float2 p0 = unpack2_bf16(h_cur.x), p1 = unpack2_bf16(h_cur.y);
            float2 p2 = unpack2_bf16(h_cur.z), p3 = unpack2_bf16(h_cur.w);
            acc[0] = fmaf(p0.x, w, acc[0]); acc[1] = fmaf(p0.y, w, acc[1]);
            acc[2] = fmaf(p1.x, w, acc[2]); acc[3] = fmaf(p1.y, w, acc[3]);
            acc[4] = fmaf(p2.x, w, acc[4]); acc[5] = fmaf(p2.y, w, acc[5]);
            acc[6] = fmaf(p3.x, w, acc[6]); acc[7] = fmaf(p3.y, w, acc[7]);
        }
        if (gc) {
            float cw = val ? nr_cur * ni : 0.f;
            float2 q0 = unpack2_bf16(g_cur.x), q1 = unpack2_bf16(g_cur.y);
            float2 q2 = unpack2_bf16(g_cur.z), q3 = unpack2_bf16(g_cur.w);
            gacc[0] = fmaf(q0.x, cw, gacc[0]); gacc[1] = fmaf(q0.y, cw, gacc[1]);
            gacc[2] = fmaf(q1.x, cw, gacc[2]); gacc[3] = fmaf(q1.y, cw, gacc[3]);
            gacc[4] = fmaf(q2.x, cw, gacc[4]); gacc[5] = fmaf(q2.y, cw, gacc[5]);
            gacc[6] = fmaf(q3.x, cw, gacc[6]); gacc[7] = fmaf(q3.y, cw, gacc[7]);
        }
        a_cur = a_nxt; h_cur = h_nxt; g_cur = g_nxt; nr_cur = nr_nxt;
    }
    for (int j4 = 64; j4 < deg; j4 += 4) {     // rare tail: deg > 64
        int idx = j4 + e;
        bool val = idx < deg;
        unsigned s = val ? csr_src[beg + idx] : (unsigned)i;
        float4 a = as1v[s];
        float w = val ? __expf(leakyf(sel4(a, h) + dvh)) : 0.f;
        sumw += w;
        uint4 hv = hv4[(size_t)s * 20 + c];
        float2 p0 = unpack2_bf16(hv.x), p1 = unpack2_bf16(hv.y);
        float2 p2 = unpack2_bf16(hv.z), p3 = unpack2_bf16(hv.w);
        acc[0] = fmaf(p0.x, w, acc[0]); acc[1] = fmaf(p0.y, w, acc[1]);
        acc[2] = fmaf(p1.x, w, acc[2]); acc[3] = fmaf(p1.y, w, acc[3]);
        acc[4] = fmaf(p2.x, w, acc[4]); acc[5] = fmaf(p2.y, w, acc[5]);
        acc[6] = fmaf(p3.x, w, acc[6]); acc[7] = fmaf(p3.y, w, acc[7]);
        if (gc) {
            float cw = val ? nrm[s] * ni : 0.f;
            uint4 gv = hv4[(size_t)s * 20 + 16 + c];
            float2 q0 = unpack2_bf16(gv.x), q1 = unpack2_bf16(gv.y);
            float2 q2 = unpack2_bf16(gv.z), q3 = unpack2_bf16(gv.w);
            gacc[0] = fmaf(q0.x, cw, gacc[0]); gacc[1] = fmaf(q0.y, cw, gacc[1]);
            gacc[2] = fmaf(q1.x, cw, gacc[2]); gacc[3] = fmaf(q1.y, cw, gacc[3]);
            gacc[4] = fmaf(q2.x, cw, gacc[4]); gacc[5] = fmaf(q2.y, cw, gacc[5]);
            gacc[6] = fmaf(q3.x, cw, gacc[6]); gacc[7] = fmaf(q3.y, cw, gacc[7]);
        }
    }

#pragma unroll
    for (int t = 0; t < 8; ++t) {
        acc[t]  += __shfl_xor(acc[t], 16, 64);
        acc[t]  += __shfl_xor(acc[t], 32, 64);
        gacc[t] += __shfl_xor(gacc[t], 16, 64);
        gacc[t] += __shfl_xor(gacc[t], 32, 64);
    }
    sumw += __shfl_xor(sumw, 16, 64);
    sumw += __shfl_xor(sumw, 32, 64);
    const float ssh = sumw + eself;

    if (e == 0) {                             // lanes 0-15: final 8ch each
        float inv = 1.f / ssh;
        float4 b0 = *(const float4*)&gat_b1[c * 8];
        float4 b1 = *(const float4*)&gat_b1[c * 8 + 4];
        float o[8] = {acc[0] * inv + b0.x, acc[1] * inv + b0.y,
                      acc[2] * inv + b0.z, acc[3] * inv + b0.w,
                      acc[4] * inv + b1.x, acc[5] * inv + b1.y,
                      acc[6] * inv + b1.z, acc[7] * inv + b1.w};
#pragma unroll
        for (int t = 0; t < 8; ++t) o[t] = o[t] > 0.f ? o[t] : __expf(o[t]) - 1.f;
        uint4 pv = make_uint4(pack2_bf16(o[0], o[1]), pack2_bf16(o[2], o[3]),
                              pack2_bf16(o[4], o[5]), pack2_bf16(o[6], o[7]));
        ((uint4*)xgb)[(size_t)i * 16 + c] = pv;
        if (gc) {                             // lanes 0-3: final gcn 8ch each
            float4 c0 = *(const float4*)&gcn_b1[c * 8];
            float4 c1 = *(const float4*)&gcn_b1[c * 8 + 4];
            float g[8] = {fmaxf(gacc[0] + c0.x, 0.f), fmaxf(gacc[1] + c0.y, 0.f),
                          fmaxf(gacc[2] + c0.z, 0.f), fmaxf(gacc[3] + c0.w, 0.f),
                          fmaxf(gacc[4] + c1.x, 0.f), fmaxf(gacc[5] + c1.y, 0.f),
                          fmaxf(gacc[6] + c1.z, 0.f), fmaxf(gacc[7] + c1.w, 0.f)};
            uint4 gv = make_uint4(pack2_bf16(g[0], g[1]), pack2_bf16(g[2], g[3]),
                                  pack2_bf16(g[4], g[5]), pack2_bf16(g[6], g[7]));
            ((uint4*)gaccb)[(size_t)i * 4 + c] = gv;
        }
    }
}

// ---------------- fused layer-2 aggregation: single-pass (R2 config) --------
// Lane L: edge-slot e=L&3, chunk c=L>>2 (10 chunks: c<5 GAT / c>=5 GCN).
// 2-deep pipeline; writes cat (head stays a separate GEMM - fusion measured
// twice as a large regression: gather concurrency collapses).
__global__ __launch_bounds__(256) void agg2_fused_kernel(
    const unsigned* __restrict__ hg_b, const float* __restrict__ as2,
    const float* __restrict__ ad2, const float* __restrict__ nrm,
    const unsigned* __restrict__ rs, const unsigned* __restrict__ csr_src,
    const float* __restrict__ gat_b2, const float* __restrict__ gcn_b2,
    const float* __restrict__ wc_p, const float* __restrict__ wt_p,
    float* __restrict__ cat, int n)
{
    const int wid = threadIdx.x >> 6;
    const int lane = threadIdx.x & 63;
    const int i = blockIdx.x * 4 + wid;
    if (i >= n) return;
    const unsigned beg = rs[i];
    const int deg = (int)(rs[i + 1] - beg);
    const int e = lane & 3, c = lane >> 2;
    const bool act = c < 10, isgat = c < 5;
    const float adv = ad2[i];
    const float ni = nrm[i];
    const uint4* hgv = (const uint4*)hg_b;    // row = 10 uint4

    unsigned pre = (lane < deg) ? csr_src[beg + lane] : (unsigned)i;
    const float eself = __expf(leakyf(as2[i] + adv));

    float acc[8];
#pragma unroll
    for (int t = 0; t < 8; ++t) acc[t] = 0.f;
    float sumw = 0.f;

    if (act && e == 0) {                      // self contribution once
        uint4 hv = hgv[(size_t)i * 10 + c];
        float sw = isgat ? eself : ni * ni;
        float2 p0 = unpack2_bf16(hv.x), p1 = unpack2_bf16(hv.y);
        float2 p2 = unpack2_bf16(hv.z), p3 = unpack2_bf16(hv.w);
        acc[0] = p0.x * sw; acc[1] = p0.y * sw;
        acc[2] = p1.x * sw; acc[3] = p1.y * sw;
        acc[4] = p2.x * sw; acc[5] = p2.y * sw;
        acc[6] = p3.x * sw; acc[7] = p3.y * sw;
    }

    const int dfast = deg < 64 ? deg : 64;
    const int steps = (dfast + 3) >> 2;

    float aw_cur = 0.f;
    uint4 h_cur = make_uint4(0u, 0u, 0u, 0u);
    if (steps > 0) {
        unsigned s = __shfl(pre, e, 64);
        if (e >= deg) s = (unsigned)i;
        if (act) { aw_cur = isgat ? as2[s] : nrm[s]; h_cur = hgv[(size_t)s * 10 + c]; }
    }
    for (int j = 0; j < steps; ++j) {
        float aw_nxt = aw_cur;
        uint4 h_nxt = h_cur;
        if (j + 1 < steps) {
            int idx = (j + 1) * 4 + e;
            unsigned s = __shfl(pre, idx, 64);
            if (idx >= deg) s = (unsigned)i;
            if (act) { aw_nxt = isgat ? as2[s] : nrm[s]; h_nxt = hgv[(size_t)s * 10 + c]; }
        }
        const bool val = (j * 4 + e) < deg;
        float w;
        if (isgat) {
            w = __expf(leakyf(aw_cur + adv));
            w = val ? w : 0.f;
            sumw += w;
        } else {
            w = val ? aw_cur * ni : 0.f;
        }
        if (act) {
            float2 p0 = unpack2_bf16(h_cur.x), p1 = unpack2_bf16(h_cur.y);
            float2 p2 = unpack2_bf16(h_cur.z), p3 = unpack2_bf16(h_cur.w);
            acc[0] = fmaf(p0.x, w, acc[0]); acc[1] = fmaf(p0.y, w, acc[1]);
            acc[2] = fmaf(p1.x, w, acc[2]); acc[3] = fmaf(p1.y, w, acc[3]);
            acc[4] = fmaf(p2.x, w, acc[4]); acc[5] = fmaf(p2.y, w, acc[5]);
            acc[6] = fmaf(p3.x, w, acc[6]); acc[7] = fmaf(p3.y, w, acc[7]);
        }
        aw_cur = aw_nxt; h_cur = h_nxt;
    }
    for (int j4 = 64; j4 < deg; j4 += 4) {    // rare tail
        int idx = j4 + e;
        bool val = idx < deg;
        unsigned s = val ? csr_src[beg + idx] : (unsigned)i;
        if (act) {
            float aw = isgat ? as2[s] : nrm[s];
            float w;
            if (isgat) {
                w = val ? __expf(leakyf(aw + adv)) : 0.f;
                sumw += w;
            } else {
                w = val ? aw * ni : 0.f;
            }
            uint4 hv = hgv[(size_t)s * 10 + c];
            float2 p0 = unpack2_bf16(hv.x), p1 = unpack2_bf16(hv.y);
            float2 p2 = unpack2_bf16(hv.z), p3 = unpack2_bf16(hv.w);
            acc[0] = fmaf(p0.x, w, acc[0]); acc[1] = fmaf(p0.y, w, acc[1]);
            acc[2] = fmaf(p1.x, w, acc[2]); acc[3] = fmaf(p1.y, w, acc[3]);
            acc[4] = fmaf(p2.x, w, acc[4]); acc[5] = fmaf(p2.y, w, acc[5]);
            acc[6] = fmaf(p3.x, w, acc[6]); acc[7] = fmaf(p3.y, w, acc[7]);
        }
    }

#pragma unroll
    for (int t = 0; t < 8; ++t) {
        acc[t] += __shfl_xor(acc[t], 1, 64);
        acc[t] += __shfl_xor(acc[t], 2, 64);
    }
    sumw += __shfl_xor(sumw, 1, 64);
    sumw += __shfl_xor(sumw, 2, 64);
    const float ssum = sumw + eself;

    if (act && e == 0) {
        if (isgat) {
            float inv = 1.f / ssum, wt = *wt_p;
            float4 b0 = *(const float4*)&gat_b2[c * 8];
            float4 b1 = *(const float4*)&gat_b2[c * 8 + 4];
            float4 o0 = make_float4((acc[0] * inv + b0.x) * wt, (acc[1] * inv + b0.y) * wt,
                                    (acc[2] * inv + b0.z) * wt, (acc[3] * inv + b0.w) * wt);
            float4 o1 = make_float4((acc[4] * inv + b1.x) * wt, (acc[5] * inv + b1.y) * wt,
                                    (acc[6] * inv + b1.z) * wt, (acc[7] * inv + b1.w) * wt);
            *(float4*)&cat[(size_t)i * 80 + 40 + c * 8]     = o0;
            *(float4*)&cat[(size_t)i * 80 + 40 + c * 8 + 4] = o1;
        } else {
            float wc = *wc_p;
            int g = c - 5;
            float4 b0 = *(const float4*)&gcn_b2[g * 8];
            float4 b1 = *(const float4*)&gcn_b2[g * 8 + 4];
            float4 o0 = make_float4((acc[0] + b0.x) * wc, (acc[1] + b0.y) * wc,
                                    (acc[2] + b0.z) * wc, (acc[3] + b0.w) * wc);
            float4 o1 = make_float4((acc[4] + b1.x) * wc, (acc[5] + b1.y) * wc,
                                    (acc[6] + b1.z) * wc, (acc[7] + b1.w) * wc);
            *(float4*)&cat[(size_t)i * 80 + g * 8]     = o0;
            *(float4*)&cat[(size_t)i * 80 + g * 8 + 4] = o1;
        }
    }
}

// ---------------- host ------------------------------------------------------
extern "C" void kernel_launch(void* const* d_in, const int* in_sizes, int n_in,
                              void* d_out, int out_size, void* d_ws, size_t ws_size,
                              hipStream_t stream)
{
    const float* x        = (const float*)d_in[0];
    const int*   eidx     = (const int*)d_in[1];
    const float* gat_W1   = (const float*)d_in[2];
    const float* att_s1   = (const float*)d_in[3];
    const float* att_d1   = (const float*)d_in[4];
    const float* gat_b1   = (const float*)d_in[5];
    const float* gat_W2   = (const float*)d_in[6];
    const float* att_s2   = (const float*)d_in[7];
    const float* att_d2   = (const float*)d_in[8];
    const float* gat_b2   = (const float*)d_in[9];
    const float* gcn_W1   = (const float*)d_in[10];
    const float* gcn_b1   = (const float*)d_in[11];
    const float* gcn_W2   = (const float*)d_in[12];
    const float* gcn_b2   = (const float*)d_in[13];
    const float* lin_W    = (const float*)d_in[14];
    const float* lin_b    = (const float*)d_in[15];
    const float* wc_p     = (const float*)d_in[16];
    const float* wt_p     = (const float*)d_in[17];

    const int n = in_sizes[0] / F_IN;      // 50000
    const int e = in_sizes[1] / 2;         // 800000
    const int* src = eidx;
    const int* dst = eidx + e;
    const int NBUCK = (n + 127) >> 7;      // 391

    char* p = (char*)d_ws;
    auto alloc = [&](size_t bytes) -> void* {
        void* r = (void*)p;
        p += (bytes + 255) & ~(size_t)255;
        return r;
    };
    unsigned* counts  = (unsigned*)alloc((size_t)n * 4);
    unsigned* rs      = (unsigned*)alloc((size_t)(n + 1) * 4);
    unsigned* cursor  = (unsigned*)alloc((size_t)n * 4);
    unsigned* partials= (unsigned*)alloc(256 * 4);
    unsigned* bcnt    = (unsigned*)alloc((size_t)(NBUCK + 1) * 4);
    unsigned* csr_src = (unsigned*)alloc((size_t)e * 4);
    uint4*    wbf     = (uint4*)alloc(40 * 64 * 16);
    float* nrm     = (float*)alloc((size_t)n * 4);
    float* as1     = (float*)alloc((size_t)n * 4 * 4);
    float* ad1     = (float*)alloc((size_t)n * 4 * 4);
    float* as2     = (float*)alloc((size_t)n * 4);
    float* ad2     = (float*)alloc((size_t)n * 4);
    float* cat     = (float*)alloc((size_t)n * 80 * 4);   // agg2 out; earlier: bpair, hb
    unsigned* hg_b = (unsigned*)alloc((size_t)n * 40 * 4);
    float* xg      = (float*)alloc((size_t)n * F_IN * 4); // xgb bf16
    unsigned* gaccb= (unsigned*)alloc((size_t)n * 16 * 4);
    // aliases with disjoint lifetimes (stream-ordered):
    unsigned* bpair = (unsigned*)cat;
    uint2*    ovf   = (uint2*)(bpair + (size_t)NBUCK * BCAP);
    unsigned* hb    = (unsigned*)cat;                     // [n][80] combined h1 after CSR build
    unsigned* xgb   = (unsigned*)xg;
    unsigned* ovf_cnt = bcnt + NBUCK;

    const int NB = (n + 255) / 256;
    const int WB = (n + 3) / 4;
    const int SB = (e + SCHUNK - 1) / SCHUNK;

    // ---- W pre-pack (also zeroes bcnt + partials; replaces memset) ----
    wb_prep_kernel<<<40, 64, 0, stream>>>(gat_W1, gcn_W1, wbf, bcnt, NBUCK + 1, partials);

    // ---- CSR build (bucket_count also emits per-scan-block partial sums) ----
    bucket_scatter_kernel<<<SB, 256, 0, stream>>>(src, dst, bcnt, bpair, ovf_cnt, ovf, e, NBUCK);
    bucket_count_kernel<<<NBUCK, 256, 0, stream>>>(bcnt, bpair, ovf_cnt, ovf, counts, partials, n);
    scan_partials_kernel<<<1, 256, 0, stream>>>(partials, rs, NB, n);
    scan_write_kernel<<<NB, 256, 0, stream>>>(counts, partials, rs, nrm, n);
    bucket_place_kernel<<<NBUCK, 256, 0, stream>>>(bcnt, bpair, rs, csr_src, cursor, n);
    overflow_fill_kernel<<<1, 256, 0, stream>>>(ovf_cnt, ovf, cursor, csr_src);

    // ---- MFMA first-layer GEMM (fused logits1) ----
    gemm1_mfma_kernel<<<(n + 63) / 64, 256, 0, stream>>>(x, wbf, att_s1, att_d1,
                                                         hb, as1, ad1, n);

    // ---- fused layer-1 aggregation (single-pass GAT softmax + GCN norm) ----
    agg1_fused_kernel<<<WB, 256, 0, stream>>>(hb, as1, ad1, nrm, rs, csr_src,
                                              gat_b1, gcn_b1, xgb, gaccb, n);

    // ---- layer-2 GEMMs into hg_b (gat gemm fuses logits2) ----
    gemm_tile_bb<32, 40, 128, 32, 40, 20><<<(n + 127) / 128, 320, 0, stream>>>(gaccb, gcn_W2, hg_b, n);
    gemm2_gat_kernel<<<(n + 127) / 128, 320, 0, stream>>>(xgb, gat_W2, att_s2, att_d2,
                                                          hg_b, as2, ad2, n);

    // ---- fused layer-2 aggregation -> cat ----
    agg2_fused_kernel<<<WB, 256, 0, stream>>>(hg_b, as2, ad2, nrm, rs, csr_src,
                                              gat_b2, gcn_b2, wc_p, wt_p, cat, n);

    // ---- head ----
    gemm_tile<80, 40, 128, 40><<<(n + 127) / 128, 320, 0, stream>>>(cat, lin_W, lin_b, (float*)d_out, n);
}

// Round 7
// 295.145 us; speedup vs baseline: 1.2630x; 1.0195x over previous
//
#include <hip/hip_runtime.h>
#include <math.h>

#define F_IN   128
#define HIDC   32
#define NHEAD  4
#define CDIM   40
#define NEG_SLOPE 0.2f
#define BCAP   4096
#define OVCAP  16384
#define SCHUNK 4096

typedef __attribute__((ext_vector_type(8))) short bf16x8;   // 8 bf16 = 4 VGPRs
typedef __attribute__((ext_vector_type(4))) float f32x4;    // MFMA C/D

__device__ __forceinline__ float leakyf(float x) { return x > 0.f ? x : NEG_SLOPE * x; }

__device__ __forceinline__ float sel4(float4 v, int h) {
    return (h == 0) ? v.x : (h == 1) ? v.y : (h == 2) ? v.z : v.w;
}
__device__ __forceinline__ unsigned pack2_bf16(float a, float b) {
    unsigned ua = __float_as_uint(a);
    unsigned ub = __float_as_uint(b);
    ua = (ua + 0x7FFFu + ((ua >> 16) & 1u)) >> 16;
    ub = (ub + 0x7FFFu + ((ub >> 16) & 1u)) >> 16;
    return ua | (ub << 16);
}
__device__ __forceinline__ float2 unpack2_bf16(unsigned p) {
    return make_float2(__uint_as_float(p << 16), __uint_as_float(p & 0xFFFF0000u));
}

// ---- W pre-pack into MFMA B-fragment order + bcnt/partials zeroing --------
__global__ void wb_prep_kernel(const float* __restrict__ Wg, const float* __restrict__ Wc,
                               uint4* __restrict__ wbf, unsigned* __restrict__ bcnt,
                               int nbuck1, unsigned* __restrict__ partials)
{
    int b = blockIdx.x;            // nt*4 + ks, 0..39
    int lane = threadIdx.x;        // 0..63
    int gtid = b * 64 + lane;
    if (gtid < nbuck1) bcnt[gtid] = 0u;
    if (gtid < 256) partials[gtid] = 0u;
    int nt = b >> 2, ks = b & 3;
    int c = nt * 16 + (lane & 15);
    int k0 = ks * 32 + (lane >> 4) * 8;
    unsigned u[4];
#pragma unroll
    for (int jj = 0; jj < 4; ++jj) {
        int k = k0 + 2 * jj;
        float a0 = (c < 128) ? Wg[(size_t)k * 128 + c] : Wc[(size_t)k * 32 + (c - 128)];
        float a1 = (c < 128) ? Wg[(size_t)(k + 1) * 128 + c] : Wc[(size_t)(k + 1) * 32 + (c - 128)];
        u[jj] = pack2_bf16(a0, a1);
    }
    wbf[(size_t)b * 64 + lane] = make_uint4(u[0], u[1], u[2], u[3]);
}

// ---- merged dispatch: gemm1 (MFMA, blocks [0,G1)) + bucket scatter --------
// gemm1 is independent of the CSR build (bpair is no longer aliased with hb),
// so both run concurrently in one dispatch; the CSR chain follows.
// gemm1 output row: hb[node][80] = 64 GAT (128ch bf16) + 16 GCN (32ch bf16).
__global__ __launch_bounds__(256) void scatter_gemm1_kernel(
    const int* __restrict__ src, const int* __restrict__ dst,
    unsigned* __restrict__ bcnt, unsigned* __restrict__ bpair,
    unsigned* __restrict__ ovf_cnt, uint2* __restrict__ ovf,
    int e, int nbuck, int G1,
    const float* __restrict__ X, const uint4* __restrict__ wbf,
    const float* __restrict__ aw_s, const float* __restrict__ aw_d,
    unsigned* __restrict__ hb,
    float* __restrict__ as1, float* __restrict__ ad1, int n)
{
    __shared__ unsigned hist[512];
    __shared__ unsigned hbase[512];
    __shared__ float Ct[64][164];
    __shared__ float sw[128], dw[128];
    const int tid = threadIdx.x;

    if ((int)blockIdx.x >= G1) {
        // ---------------- bucket scatter ----------------
        const int t = tid;
        const int lo = ((int)blockIdx.x - G1) * SCHUNK;
        const int hi = min(lo + SCHUNK, e);
        for (int i = t; i < nbuck; i += 256) hist[i] = 0;
        __syncthreads();
        for (int i = lo + t; i < hi; i += 256)
            atomicAdd(&hist[((unsigned)dst[i]) >> 7], 1u);
        __syncthreads();
        for (int i = t; i < nbuck; i += 256) {
            unsigned c = hist[i];
            hbase[i] = c ? atomicAdd(&bcnt[i], c) : 0u;
            hist[i] = 0;
        }
        __syncthreads();
        for (int i = lo + t; i < hi; i += 256) {
            unsigned s = (unsigned)src[i], d = (unsigned)dst[i];
            unsigned b = d >> 7;
            unsigned pos = hbase[b] + atomicAdd(&hist[b], 1u);
            if (pos < BCAP) bpair[(size_t)b * BCAP + pos] = s | ((d & 127u) << 16);
            else {
                unsigned o = atomicAdd(ovf_cnt, 1u);
                if (o < OVCAP) ovf[o] = make_uint2(s, d);
            }
        }
        return;
    }

    // ---------------- gemm1 (MFMA) + fused logits1 ----------------
    const int w = tid >> 6, lane = tid & 63;
    const int m = lane & 15, q = lane >> 4;
    const int node0 = blockIdx.x * 64;
    if (tid < 128) { sw[tid] = aw_s[tid]; dw[tid] = aw_d[tid]; }

    f32x4 acc[10];
#pragma unroll
    for (int t = 0; t < 10; ++t) acc[t] = (f32x4){0.f, 0.f, 0.f, 0.f};

    const int row = node0 + w * 16 + m;
    const bool rv = row < n;
#pragma unroll
    for (int ks = 0; ks < 4; ++ks) {
        uint4 pa = make_uint4(0u, 0u, 0u, 0u);
        if (rv) {
            const float* xr = X + (size_t)row * 128 + ks * 32 + q * 8;
            float4 a0 = *(const float4*)xr;
            float4 a1 = *(const float4*)(xr + 4);
            pa = make_uint4(pack2_bf16(a0.x, a0.y), pack2_bf16(a0.z, a0.w),
                            pack2_bf16(a1.x, a1.y), pack2_bf16(a1.z, a1.w));
        }
        bf16x8 af = *(bf16x8*)&pa;
#pragma unroll
        for (int nt = 0; nt < 10; ++nt) {
            uint4 pb = wbf[(size_t)(nt * 4 + ks) * 64 + lane];
            bf16x8 bfv = *(bf16x8*)&pb;
            acc[nt] = __builtin_amdgcn_mfma_f32_16x16x32_bf16(af, bfv, acc[nt], 0, 0, 0);
        }
    }
#pragma unroll
    for (int nt = 0; nt < 10; ++nt)
#pragma unroll
        for (int r = 0; r < 4; ++r)
            Ct[w * 16 + q * 4 + r][nt * 16 + m] = acc[nt][r];
    __syncthreads();

    for (int i = tid; i < 64 * 64; i += 256) {
        int nd = i >> 6, u = i & 63;
        int gn = node0 + nd;
        if (gn < n)
            hb[(size_t)gn * 80 + u] = pack2_bf16(Ct[nd][2 * u], Ct[nd][2 * u + 1]);
    }
    for (int i = tid; i < 64 * 16; i += 256) {
        int nd = i >> 4, u = i & 15;
        int gn = node0 + nd;
        if (gn < n)
            hb[(size_t)gn * 80 + 64 + u] = pack2_bf16(Ct[nd][128 + 2 * u], Ct[nd][128 + 2 * u + 1]);
    }
    {
        int nd = tid >> 2, h = tid & 3;
        int gn = node0 + nd;
        if (gn < n) {
            float s = 0.f, d = 0.f;
#pragma unroll
            for (int k = 0; k < HIDC; ++k) {
                float v = Ct[nd][h * HIDC + k];
                s = fmaf(v, sw[h * HIDC + k], s);
                d = fmaf(v, dw[h * HIDC + k], d);
            }
            as1[(size_t)gn * 4 + h] = s;
            ad1[(size_t)gn * 4 + h] = d;
        }
    }
}

// ---------------- tiled GEMM (fp32 in/out, head) ----------------------------
template<int K, int OUTC, int BN, int BK, int OSTRIDE = OUTC>
__global__ __launch_bounds__((OUTC / 4) * (BN / 4)) void gemm_tile(
    const float* __restrict__ X, const float* __restrict__ W,
    const float* __restrict__ bias, float* __restrict__ Y, int n)
{
    constexpr int CG = OUTC / 4;
    constexpr int NG = BN / 4;
    constexpr int NT = CG * NG;
    __shared__ float Xs[BK][BN + 4];
    __shared__ float Ws[BK][OUTC];
    const int tid = threadIdx.x;
    const int cg = tid % CG, ng = tid / CG;
    const int node0 = blockIdx.x * BN;
    float acc[4][4] = {};

    for (int kb = 0; kb < K; kb += BK) {
        for (int idx = tid; idx < BN * (BK / 4); idx += NT) {
            int nd = idx / (BK / 4);
            int kq = idx % (BK / 4);
            int gnode = node0 + nd;
            float4 v = (gnode < n) ? *(const float4*)&X[(size_t)gnode * K + kb + kq * 4]
                                   : make_float4(0.f, 0.f, 0.f, 0.f);
            Xs[kq * 4 + 0][nd] = v.x;
            Xs[kq * 4 + 1][nd] = v.y;
            Xs[kq * 4 + 2][nd] = v.z;
            Xs[kq * 4 + 3][nd] = v.w;
        }
        for (int idx = tid; idx < BK * CG; idx += NT) {
            int kk = idx / CG;
            int cq = idx % CG;
            *(float4*)&Ws[kk][cq * 4] = *(const float4*)&W[(size_t)(kb + kk) * OUTC + cq * 4];
        }
        __syncthreads();
#pragma unroll
        for (int k = 0; k < BK; ++k) {
            float4 xv = *(const float4*)&Xs[k][ng * 4];
            float4 wv = *(const float4*)&Ws[k][cg * 4];
            float xa[4] = {xv.x, xv.y, xv.z, xv.w};
            float wa[4] = {wv.x, wv.y, wv.z, wv.w};
#pragma unroll
            for (int j = 0; j < 4; ++j)
#pragma unroll
                for (int c = 0; c < 4; ++c)
                    acc[j][c] = fmaf(xa[j], wa[c], acc[j][c]);
        }
        __syncthreads();
    }

    float4 bv = make_float4(0.f, 0.f, 0.f, 0.f);
    if (bias) bv = *(const float4*)&bias[cg * 4];
#pragma unroll
    for (int j = 0; j < 4; ++j) {
        int gnode = node0 + ng * 4 + j;
        if (gnode < n) {
            float4 o = make_float4(acc[j][0] + bv.x, acc[j][1] + bv.y,
                                   acc[j][2] + bv.z, acc[j][3] + bv.w);
            *(float4*)&Y[(size_t)gnode * OSTRIDE + cg * 4] = o;
        }
    }
}

// bf16-in (packed), bf16-out variant (gcn L2 gemm)
template<int K, int OUTC, int BN, int BK, int OSTRIDE_U, int OFF_U>
__global__ __launch_bounds__((OUTC / 4) * (BN / 4)) void gemm_tile_bb(
    const unsigned* __restrict__ Xb, const float* __restrict__ W,
    unsigned* __restrict__ Yb, int n)
{
    constexpr int CG = OUTC / 4;
    constexpr int NG = BN / 4;
    constexpr int NT = CG * NG;
    __shared__ float Xs[BK][BN + 4];
    __shared__ float Ws[BK][OUTC];
    const int tid = threadIdx.x;
    const int cg = tid % CG, ng = tid / CG;
    const int node0 = blockIdx.x * BN;
    float acc[4][4] = {};

    for (int kb = 0; kb < K; kb += BK) {
        for (int idx = tid; idx < BN * (BK / 8); idx += NT) {
            int nd = idx / (BK / 8);
            int kq = idx % (BK / 8);
            int gnode = node0 + nd;
            uint4 v = (gnode < n) ? *(const uint4*)&Xb[(size_t)gnode * (K / 2) + kb / 2 + kq * 4]
                                  : make_uint4(0u, 0u, 0u, 0u);
            float2 a = unpack2_bf16(v.x), b = unpack2_bf16(v.y);
            float2 c = unpack2_bf16(v.z), d = unpack2_bf16(v.w);
            Xs[kq * 8 + 0][nd] = a.x; Xs[kq * 8 + 1][nd] = a.y;
            Xs[kq * 8 + 2][nd] = b.x; Xs[kq * 8 + 3][nd] = b.y;
            Xs[kq * 8 + 4][nd] = c.x; Xs[kq * 8 + 5][nd] = c.y;
            Xs[kq * 8 + 6][nd] = d.x; Xs[kq * 8 + 7][nd] = d.y;
        }
        for (int idx = tid; idx < BK * CG; idx += NT) {
            int kk = idx / CG;
            int cq = idx % CG;
            *(float4*)&Ws[kk][cq * 4] = *(const float4*)&W[(size_t)(kb + kk) * OUTC + cq * 4];
        }
        __syncthreads();
#pragma unroll
        for (int k = 0; k < BK; ++k) {
            float4 xv = *(const float4*)&Xs[k][ng * 4];
            float4 wv = *(const float4*)&Ws[k][cg * 4];
            float xa[4] = {xv.x, xv.y, xv.z, xv.w};
            float wa[4] = {wv.x, wv.y, wv.z, wv.w};
#pragma unroll
            for (int j = 0; j < 4; ++j)
#pragma unroll
                for (int c = 0; c < 4; ++c)
                    acc[j][c] = fmaf(xa[j], wa[c], acc[j][c]);
        }
        __syncthreads();
    }

#pragma unroll
    for (int j = 0; j < 4; ++j) {
        int gnode = node0 + ng * 4 + j;
        if (gnode < n) {
            uint2 pb = make_uint2(pack2_bf16(acc[j][0], acc[j][1]),
                                  pack2_bf16(acc[j][2], acc[j][3]));
            *(uint2*)&Yb[(size_t)gnode * OSTRIDE_U + OFF_U + cg * 2] = pb;
        }
    }
}

// ---- GAT L2 GEMM (bf16 in/out) + fused logits2 epilogue --------------------
__global__ __launch_bounds__(320) void gemm2_gat_kernel(
    const unsigned* __restrict__ Xb, const float* __restrict__ W,
    const float* __restrict__ aw_s, const float* __restrict__ aw_d,
    unsigned* __restrict__ Yb, float* __restrict__ as2, float* __restrict__ ad2, int n)
{
    constexpr int K = 128, OUTC = 40, BN = 128, BK = 32;
    constexpr int CG = OUTC / 4, NT = 320;
    __shared__ float smem[32 * 132 + 32 * 40];     // 5504 floats
    float* Xs = smem;                               // [32][132]
    float* Ws = smem + 32 * 132;                    // [32][40]
    const int tid = threadIdx.x;
    const int cg = tid % CG, ng = tid / CG;
    const int node0 = blockIdx.x * BN;
    float acc[4][4] = {};

    for (int kb = 0; kb < K; kb += BK) {
        for (int idx = tid; idx < BN * (BK / 8); idx += NT) {
            int nd = idx / (BK / 8);
            int kq = idx % (BK / 8);
            int gnode = node0 + nd;
            uint4 v = (gnode < n) ? *(const uint4*)&Xb[(size_t)gnode * (K / 2) + kb / 2 + kq * 4]
                                  : make_uint4(0u, 0u, 0u, 0u);
            float2 a = unpack2_bf16(v.x), b = unpack2_bf16(v.y);
            float2 c = unpack2_bf16(v.z), d = unpack2_bf16(v.w);
            Xs[(kq * 8 + 0) * 132 + nd] = a.x; Xs[(kq * 8 + 1) * 132 + nd] = a.y;
            Xs[(kq * 8 + 2) * 132 + nd] = b.x; Xs[(kq * 8 + 3) * 132 + nd] = b.y;
            Xs[(kq * 8 + 4) * 132 + nd] = c.x; Xs[(kq * 8 + 5) * 132 + nd] = c.y;
            Xs[(kq * 8 + 6) * 132 + nd] = d.x; Xs[(kq * 8 + 7) * 132 + nd] = d.y;
        }
        for (int idx = tid; idx < BK * CG; idx += NT) {
            int kk = idx / CG;
            int cq = idx % CG;
            *(float4*)&Ws[kk * 40 + cq * 4] = *(const float4*)&W[(size_t)(kb + kk) * OUTC + cq * 4];
        }
        __syncthreads();
#pragma unroll
        for (int k = 0; k < BK; ++k) {
            float4 xv = *(const float4*)&Xs[k * 132 + ng * 4];
            float4 wv = *(const float4*)&Ws[k * 40 + cg * 4];
            float xa[4] = {xv.x, xv.y, xv.z, xv.w};
            float wa[4] = {wv.x, wv.y, wv.z, wv.w};
#pragma unroll
            for (int j = 0; j < 4; ++j)
#pragma unroll
                for (int c = 0; c < 4; ++c)
                    acc[j][c] = fmaf(xa[j], wa[c], acc[j][c]);
        }
        __syncthreads();
    }

    // global bf16 write + stage Ct for logits
    float* Ct  = smem;              // [128][41]
    float* sww = smem + 128 * 41;   // [40]
    float* dww = sww + 40;          // [40]
#pragma unroll
    for (int j = 0; j < 4; ++j) {
        int gnode = node0 + ng * 4 + j;
        if (gnode < n) {
            uint2 pb = make_uint2(pack2_bf16(acc[j][0], acc[j][1]),
                                  pack2_bf16(acc[j][2], acc[j][3]));
            *(uint2*)&Yb[(size_t)gnode * 40 + cg * 2] = pb;
        }
#pragma unroll
        for (int c = 0; c < 4; ++c)
            Ct[(ng * 4 + j) * 41 + cg * 4 + c] = acc[j][c];
    }
    if (tid < 40) { sww[tid] = aw_s[tid]; dww[tid] = aw_d[tid]; }
    __syncthreads();
    if (tid < 128) {
        int gnode = node0 + tid;
        if (gnode < n) {
            float s = 0.f, d = 0.f;
#pragma unroll
            for (int c = 0; c < 40; ++c) {
                float v = Ct[tid * 41 + c];
                s = fmaf(v, sww[c], s);
                d = fmaf(v, dww[c], d);
            }
            as2[gnode] = s;
            ad2[gnode] = d;
        }
    }
}

// counts per node + per-scan-block partial sums (partials zeroed in wb_prep,
// scan-block sb = bucket b >> 1)
__global__ __launch_bounds__(256) void bucket_count_kernel(
    const unsigned* __restrict__ bcnt, const unsigned* __restrict__ bpair,
    const unsigned* __restrict__ ovf_cnt, const uint2* __restrict__ ovf,
    unsigned* __restrict__ counts, unsigned* __restrict__ partials, int n)
{
    __shared__ unsigned lc[128];
    const int b = blockIdx.x, base = b << 7;
    if (threadIdx.x < 128) lc[threadIdx.x] = 0;
    __syncthreads();
    unsigned bc = bcnt[b];
    int cnt = (int)(bc < BCAP ? bc : BCAP);
    for (int k = threadIdx.x; k < cnt; k += 256)
        atomicAdd(&lc[bpair[(size_t)b * BCAP + k] >> 16], 1u);
    unsigned oc_u = *ovf_cnt;
    int oc = (int)(oc_u < OVCAP ? oc_u : OVCAP);
    for (int k = threadIdx.x; k < oc; k += 256) {
        uint2 pp = ovf[k];
        if ((int)(pp.y >> 7) == b) atomicAdd(&lc[pp.y & 127u], 1u);
    }
    __syncthreads();
    int i = base + threadIdx.x;
    if (threadIdx.x < 128 && i < n) counts[i] = lc[threadIdx.x];
    __syncthreads();
#pragma unroll
    for (int off = 64; off > 0; off >>= 1) {
        if (threadIdx.x < off) lc[threadIdx.x] += lc[threadIdx.x + off];
        __syncthreads();
    }
    if (threadIdx.x == 0 && lc[0]) atomicAdd(&partials[b >> 1], lc[0]);
}

__global__ __launch_bounds__(256) void scan_partials_kernel(unsigned* __restrict__ partials,
                                                            unsigned* __restrict__ rs, int nb, int n)
{
    __shared__ unsigned sm[256];
    int t = threadIdx.x;
    unsigned v = (t < nb) ? partials[t] : 0u;
    sm[t] = v;
    __syncthreads();
#pragma unroll
    for (int off = 1; off < 256; off <<= 1) {
        unsigned u = (t >= off) ? sm[t - off] : 0u;
        __syncthreads();
        sm[t] += u;
        __syncthreads();
    }
    if (t < nb) partials[t] = sm[t] - v;
    if (t == 255) rs[n] = sm[255];
}

// merged: scan_write + bucket_place + overflow_fill. Block sb covers nodes
// [sb*256, sb*256+256) = buckets 2sb, 2sb+1. Local scan -> rs/nrm; rbase kept
// in LDS; place bpair entries + overflow entries for these buckets directly.
// All dependencies are intra-block; cursor array eliminated.
__global__ __launch_bounds__(256) void scan_write_place_kernel(
    const unsigned* __restrict__ counts, const unsigned* __restrict__ partials,
    unsigned* __restrict__ rs, float* __restrict__ nrm,
    const unsigned* __restrict__ bcnt, const unsigned* __restrict__ bpair,
    const unsigned* __restrict__ ovf_cnt, const uint2* __restrict__ ovf,
    unsigned* __restrict__ csr_src, int n, int nbuck)
{
    __shared__ unsigned sm[256];
    __shared__ unsigned rbase[256];
    __shared__ unsigned lc[256];
    const int t = threadIdx.x;
    const int sb = blockIdx.x;
    const int i = sb * 256 + t;
    unsigned c = (i < n) ? counts[i] : 0u;
    sm[t] = c;
    lc[t] = 0u;
    __syncthreads();
#pragma unroll
    for (int off = 1; off < 256; off <<= 1) {
        unsigned u = (t >= off) ? sm[t - off] : 0u;
        __syncthreads();
        sm[t] += u;
        __syncthreads();
    }
    const unsigned rsv = partials[sb] + sm[t] - c;
    if (i < n) {
        rs[i] = rsv;
        nrm[i] = rsqrtf((float)(c + 1u));
    }
    rbase[t] = rsv;
    __syncthreads();
#pragma unroll
    for (int half = 0; half < 2; ++half) {
        int b = 2 * sb + half;
        if (b < nbuck) {
            unsigned bc = bcnt[b];
            int cnt = (int)(bc < BCAP ? bc : BCAP);
            for (int k = t; k < cnt; k += 256) {
                unsigned v = bpair[(size_t)b * BCAP + k];
                unsigned lidx = (v >> 16) + (unsigned)(half << 7);
                unsigned r = atomicAdd(&lc[lidx], 1u);
                csr_src[rbase[lidx] + r] = v & 0xFFFFu;
            }
        }
    }
    unsigned oc_u = *ovf_cnt;
    int oc = (int)(oc_u < OVCAP ? oc_u : OVCAP);
    for (int k = t; k < oc; k += 256) {
        uint2 pp = ovf[k];
        if ((int)(pp.y >> 8) == sb) {
            unsigned lidx = pp.y & 255u;
            unsigned r = atomicAdd(&lc[lidx], 1u);
            csr_src[rbase[lidx] + r] = pp.x;
        }
    }
}

// -------- fused layer-1 aggregation: single-pass, LDS-free (R2 config) ------
// One wave per node, 2-deep pipeline (8 edges in flight), 36 VGPR / ~62% occ.
// Sits at the measured random-gather latency/BW floor (~2.6 TB/s L2-miss on
// ~146 MB); LDS staging, 2-node, deeper pipes, epilogue fusion all regress.
__global__ __launch_bounds__(256) void agg1_fused_kernel(
    const unsigned* __restrict__ hb,
    const float* __restrict__ as1, const float* __restrict__ ad1,
    const float* __restrict__ nrm,
    const unsigned* __restrict__ rs, const unsigned* __restrict__ csr_src,
    const float* __restrict__ gat_b1, const float* __restrict__ gcn_b1,
    unsigned* __restrict__ xgb, unsigned* __restrict__ gaccb, int n)
{
    const int wid = threadIdx.x >> 6;
    const int lane = threadIdx.x & 63;
    const int i = blockIdx.x * 4 + wid;
    if (i >= n) return;
    const unsigned beg = rs[i];
    const int deg = (int)(rs[i + 1] - beg);
    const float4* as1v = (const float4*)as1;
    const uint4*  hv4  = (const uint4*)hb;     // row = 20 uint4 (16 GAT + 4 GCN)

    const int e = lane >> 4, c = lane & 15;
    const int h = c >> 2;
    const bool gc = c < 4;

    const float4 dv = ((const float4*)ad1)[i];
    const float dvh = sel4(dv, h);
    const float ni  = nrm[i];

    unsigned pre = (lane < deg) ? csr_src[beg + lane] : (unsigned)i;

    const float4 av = as1v[i];
    const float eself = __expf(leakyf(sel4(av, h) + dvh));

    float acc[8], gacc[8];
#pragma unroll
    for (int t = 0; t < 8; ++t) { acc[t] = 0.f; gacc[t] = 0.f; }
    float sumw = 0.f;

    if (e == 0) {
        uint4 hv = hv4[(size_t)i * 20 + c];
        float2 p0 = unpack2_bf16(hv.x), p1 = unpack2_bf16(hv.y);
        float2 p2 = unpack2_bf16(hv.z), p3 = unpack2_bf16(hv.w);
        acc[0] = p0.x * eself; acc[1] = p0.y * eself;
        acc[2] = p1.x * eself; acc[3] = p1.y * eself;
        acc[4] = p2.x * eself; acc[5] = p2.y * eself;
        acc[6] = p3.x * eself; acc[7] = p3.y * eself;
        if (gc) {
            uint4 gv = hv4[(size_t)i * 20 + 16 + c];
            float w2s = ni * ni;
            float2 q0 = unpack2_bf16(gv.x), q1 = unpack2_bf16(gv.y);
            float2 q2 = unpack2_bf16(gv.z), q3 = unpack2_bf16(gv.w);
            gacc[0] = q0.x * w2s; gacc[1] = q0.y * w2s;
            gacc[2] = q1.x * w2s; gacc[3] = q1.y * w2s;
            gacc[4] = q2.x * w2s; gacc[5] = q2.y * w2s;
            gacc[6] = q3.x * w2s; gacc[7] = q3.y * w2s;
        }
    }

    const int dfast = deg < 64 ? deg : 64;
    const int steps = (dfast + 3) >> 2;

    float4 a_cur = make_float4(0.f, 0.f, 0.f, 0.f);
    uint4  h_cur = make_uint4(0u, 0u, 0u, 0u);
    uint4  g_cur = make_uint4(0u, 0u, 0u, 0u);
    float  nr_cur = 0.f;
    if (steps > 0) {
        unsigned s = __shfl(pre, e, 64);
        if (e >= deg) s = (unsigned)i;
        a_cur = as1v[s];
        h_cur = hv4[(size_t)s * 20 + c];
        if (gc) { g_cur = hv4[(size_t)s * 20 + 16 + c]; nr_cur = nrm[s]; }
    }
    for (int j = 0; j < steps; ++j) {
        float4 a_nxt = a_cur;
        uint4  h_nxt = h_cur, g_nxt = g_cur;
        float  nr_nxt = nr_cur;
        if (j + 1 < steps) {
            int idx = (j + 1) * 4 + e;
            unsigned s = __shfl(pre, idx, 64);
            if (idx >= deg) s = (unsigned)i;
            a_nxt = as1v[s];
            h_nxt = hv4[(size_t)s * 20 + c];
            if (gc) { g_nxt = hv4[(size_t)s * 20 + 16 + c]; nr_nxt = nrm[s]; }
        }
        const bool val = (j * 4 + e) < deg;
        float w = __expf(leakyf(sel4(a_cur, h) + dvh));
        w = val ? w : 0.f;
        sumw += w;
        {
            float2 p0 = unpack2_bf16(h_cur.x), p1 = unpack2_bf16(h_cur.y);
            float2 p2 = unpack2_bf16(h_cur.z), p3 = unpack2_bf16(h_cur.w);
            acc[0] = fmaf(p0.x, w, acc[0]); acc[1] = fmaf(p0.y, w, acc[1]);
            acc[2] = fmaf(p1.x, w, acc[2]); acc[3] = fmaf(p1.y, w, acc[3]);
            acc[4] = fmaf(p2.x, w, acc[4]); acc[5] = fmaf(p2.y, w, acc[5]);
            acc[6] = fmaf(p3.x, w, acc[6]); acc[7] = fmaf(p3.y, w, acc[7]);
        }
        if (gc) {
            float cw = val ? nr_cur * ni : 0.f;
            float2 q0 = unpack2_bf16(g_cur.x), q1 = unpack2_bf16(g_cur.y);
            float2 q2 = unpack2_bf16(g_cur.z), q3 = unpack2_bf16(g_cur.w);
            gacc[0] = fmaf(q0.x, cw, gacc[0]); gacc[1] = fmaf(q0.y, cw, gacc[1]);
            gacc[2] = fmaf(q1.x, cw, gacc[2]); gacc[3] = fmaf(q1.y, cw, gacc[3]);
            gacc[4] = fmaf(q2.x, cw, gacc[4]); gacc[5] = fmaf(q2.y, cw, gacc[5]);
            gacc[6] = fmaf(q3.x, cw, gacc[6]); gacc[7] = fmaf(q3.y, cw, gacc[7]);
        }
        a_cur = a_nxt; h_cur = h_nxt; g_cur = g_nxt; nr_cur = nr_nxt;
    }
    for (int j4 = 64; j4 < deg; j4 += 4) {     // rare tail: deg > 64
        int idx = j4 + e;
        bool val = idx < deg;
        unsigned s = val ? csr_src[beg + idx] : (unsigned)i;
        float4 a = as1v[s];
        float w = val ? __expf(leakyf(sel4(a, h) + dvh)) : 0.f;
        sumw += w;
        uint4 hv = hv4[(size_t)s * 20 + c];
        float2 p0 = unpack2_bf16(hv.x), p1 = unpack2_bf16(hv.y);
        float2 p2 = unpack2_bf16(hv.z), p3 = unpack2_bf16(hv.w);
        acc[0] = fmaf(p0.x, w, acc[0]); acc[1] = fmaf(p0.y, w, acc[1]);
        acc[2] = fmaf(p1.x, w, acc[2]); acc[3] = fmaf(p1.y, w, acc[3]);
        acc[4] = fmaf(p2.x, w, acc[4]); acc[5] = fmaf(p2.y, w, acc[5]);
        acc[6] = fmaf(p3.x, w, acc[6]); acc[7] = fmaf(p3.y, w, acc[7]);
        if (gc) {
            float cw = val ? nrm[s] * ni : 0.f;
            uint4 gv = hv4[(size_t)s * 20 + 16 + c];
            float2 q0 = unpack2_bf16(gv.x), q1 = unpack2_bf16(gv.y);
            float2 q2 = unpack2_bf16(gv.z), q3 = unpack2_bf16(gv.w);
            gacc[0] = fmaf(q0.x, cw, gacc[0]); gacc[1] = fmaf(q0.y, cw, gacc[1]);
            gacc[2] = fmaf(q1.x, cw, gacc[2]); gacc[3] = fmaf(q1.y, cw, gacc[3]);
            gacc[4] = fmaf(q2.x, cw, gacc[4]); gacc[5] = fmaf(q2.y, cw, gacc[5]);
            gacc[6] = fmaf(q3.x, cw, gacc[6]); gacc[7] = fmaf(q3.y, cw, gacc[7]);
        }
    }

#pragma unroll
    for (int t = 0; t < 8; ++t) {
        acc[t]  += __shfl_xor(acc[t], 16, 64);
        acc[t]  += __shfl_xor(acc[t], 32, 64);
        gacc[t] += __shfl_xor(gacc[t], 16, 64);
        gacc[t] += __shfl_xor(gacc[t], 32, 64);
    }
    sumw += __shfl_xor(sumw, 16, 64);
    sumw += __shfl_xor(sumw, 32, 64);
    const float ssh = sumw + eself;

    if (e == 0) {                             // lanes 0-15: final 8ch each
        float inv = 1.f / ssh;
        float4 b0 = *(const float4*)&gat_b1[c * 8];
        float4 b1 = *(const float4*)&gat_b1[c * 8 + 4];
        float o[8] = {acc[0] * inv + b0.x, acc[1] * inv + b0.y,
                      acc[2] * inv + b0.z, acc[3] * inv + b0.w,
                      acc[4] * inv + b1.x, acc[5] * inv + b1.y,
                      acc[6] * inv + b1.z, acc[7] * inv + b1.w};
#pragma unroll
        for (int t = 0; t < 8; ++t) o[t] = o[t] > 0.f ? o[t] : __expf(o[t]) - 1.f;
        uint4 pv = make_uint4(pack2_bf16(o[0], o[1]), pack2_bf16(o[2], o[3]),
                              pack2_bf16(o[4], o[5]), pack2_bf16(o[6], o[7]));
        ((uint4*)xgb)[(size_t)i * 16 + c] = pv;
        if (gc) {                             // lanes 0-3: final gcn 8ch each
            float4 c0 = *(const float4*)&gcn_b1[c * 8];
            float4 c1 = *(const float4*)&gcn_b1[c * 8 + 4];
            float g[8] = {fmaxf(gacc[0] + c0.x, 0.f), fmaxf(gacc[1] + c0.y, 0.f),
                          fmaxf(gacc[2] + c0.z, 0.f), fmaxf(gacc[3] + c0.w, 0.f),
                          fmaxf(gacc[4] + c1.x, 0.f), fmaxf(gacc[5] + c1.y, 0.f),
                          fmaxf(gacc[6] + c1.z, 0.f), fmaxf(gacc[7] + c1.w, 0.f)};
            uint4 gv = make_uint4(pack2_bf16(g[0], g[1]), pack2_bf16(g[2], g[3]),
                                  pack2_bf16(g[4], g[5]), pack2_bf16(g[6], g[7]));
            ((uint4*)gaccb)[(size_t)i * 4 + c] = gv;
        }
    }
}

// ---------------- fused layer-2 aggregation: single-pass (R2 config) --------
// Lane L: edge-slot e=L&3, chunk c=L>>2 (10 chunks: c<5 GAT / c>=5 GCN).
// 2-deep pipeline; writes cat (head stays a separate GEMM - fusion measured
// twice as a large regression: gather concurrency collapses).
__global__ __launch_bounds__(256) void agg2_fused_kernel(
    const unsigned* __restrict__ hg_b, const float* __restrict__ as2,
    const float* __restrict__ ad2, const float* __restrict__ nrm,
    const unsigned* __restrict__ rs, const unsigned* __restrict__ csr_src,
    const float* __restrict__ gat_b2, const float* __restrict__ gcn_b2,
    const float* __restrict__ wc_p, const float* __restrict__ wt_p,
    float* __restrict__ cat, int n)
{
    const int wid = threadIdx.x >> 6;
    const int lane = threadIdx.x & 63;
    const int i = blockIdx.x * 4 + wid;
    if (i >= n) return;
    const unsigned beg = rs[i];
    const int deg = (int)(rs[i + 1] - beg);
    const int e = lane & 3, c = lane >> 2;
    const bool act = c < 10, isgat = c < 5;
    const float adv = ad2[i];
    const float ni = nrm[i];
    const uint4* hgv = (const uint4*)hg_b;    // row = 10 uint4

    unsigned pre = (lane < deg) ? csr_src[beg + lane] : (unsigned)i;
    const float eself = __expf(leakyf(as2[i] + adv));

    float acc[8];
#pragma unroll
    for (int t = 0; t < 8; ++t) acc[t] = 0.f;
    float sumw = 0.f;

    if (act && e == 0) {                      // self contribution once
        uint4 hv = hgv[(size_t)i * 10 + c];
        float sw = isgat ? eself : ni * ni;
        float2 p0 = unpack2_bf16(hv.x), p1 = unpack2_bf16(hv.y);
        float2 p2 = unpack2_bf16(hv.z), p3 = unpack2_bf16(hv.w);
        acc[0] = p0.x * sw; acc[1] = p0.y * sw;
        acc[2] = p1.x * sw; acc[3] = p1.y * sw;
        acc[4] = p2.x * sw; acc[5] = p2.y * sw;
        acc[6] = p3.x * sw; acc[7] = p3.y * sw;
    }

    const int dfast = deg < 64 ? deg : 64;
    const int steps = (dfast + 3) >> 2;

    float aw_cur = 0.f;
    uint4 h_cur = make_uint4(0u, 0u, 0u, 0u);
    if (steps > 0) {
        unsigned s = __shfl(pre, e, 64);
        if (e >= deg) s = (unsigned)i;
        if (act) { aw_cur = isgat ? as2[s] : nrm[s]; h_cur = hgv[(size_t)s * 10 + c]; }
    }
    for (int j = 0; j < steps; ++j) {
        float aw_nxt = aw_cur;
        uint4 h_nxt = h_cur;
        if (j + 1 < steps) {
            int idx = (j + 1) * 4 + e;
            unsigned s = __shfl(pre, idx, 64);
            if (idx >= deg) s = (unsigned)i;
            if (act) { aw_nxt = isgat ? as2[s] : nrm[s]; h_nxt = hgv[(size_t)s * 10 + c]; }
        }
        const bool val = (j * 4 + e) < deg;
        float w;
        if (isgat) {
            w = __expf(leakyf(aw_cur + adv));
            w = val ? w : 0.f;
            sumw += w;
        } else {
            w = val ? aw_cur * ni : 0.f;
        }
        if (act) {
            float2 p0 = unpack2_bf16(h_cur.x), p1 = unpack2_bf16(h_cur.y);
            float2 p2 = unpack2_bf16(h_cur.z), p3 = unpack2_bf16(h_cur.w);
            acc[0] = fmaf(p0.x, w, acc[0]); acc[1] = fmaf(p0.y, w, acc[1]);
            acc[2] = fmaf(p1.x, w, acc[2]); acc[3] = fmaf(p1.y, w, acc[3]);
            acc[4] = fmaf(p2.x, w, acc[4]); acc[5] = fmaf(p2.y, w, acc[5]);
            acc[6] = fmaf(p3.x, w, acc[6]); acc[7] = fmaf(p3.y, w, acc[7]);
        }
        aw_cur = aw_nxt; h_cur = h_nxt;
    }
    for (int j4 = 64; j4 < deg; j4 += 4) {    // rare tail
        int idx = j4 + e;
        bool val = idx < deg;
        unsigned s = val ? csr_src[beg + idx] : (unsigned)i;
        if (act) {
            float aw = isgat ? as2[s] : nrm[s];
            float w;
            if (isgat) {
                w = val ? __expf(leakyf(aw + adv)) : 0.f;
                sumw += w;
            } else {
                w = val ? aw * ni : 0.f;
            }
            uint4 hv = hgv[(size_t)s * 10 + c];
            float2 p0 = unpack2_bf16(hv.x), p1 = unpack2_bf16(hv.y);
            float2 p2 = unpack2_bf16(hv.z), p3 = unpack2_bf16(hv.w);
            acc[0] = fmaf(p0.x, w, acc[0]); acc[1] = fmaf(p0.y, w, acc[1]);
            acc[2] = fmaf(p1.x, w, acc[2]); acc[3] = fmaf(p1.y, w, acc[3]);
            acc[4] = fmaf(p2.x, w, acc[4]); acc[5] = fmaf(p2.y, w, acc[5]);
            acc[6] = fmaf(p3.x, w, acc[6]); acc[7] = fmaf(p3.y, w, acc[7]);
        }
    }

#pragma unroll
    for (int t = 0; t < 8; ++t) {
        acc[t] += __shfl_xor(acc[t], 1, 64);
        acc[t] += __shfl_xor(acc[t], 2, 64);
    }
    sumw += __shfl_xor(sumw, 1, 64);
    sumw += __shfl_xor(sumw, 2, 64);
    const float ssum = sumw + eself;

    if (act && e == 0) {
        if (isgat) {
            float inv = 1.f / ssum, wt = *wt_p;
            float4 b0 = *(const float4*)&gat_b2[c * 8];
            float4 b1 = *(const float4*)&gat_b2[c * 8 + 4];
            float4 o0 = make_float4((acc[0] * inv + b0.x) * wt, (acc[1] * inv + b0.y) * wt,
                                    (acc[2] * inv + b0.z) * wt, (acc[3] * inv + b0.w) * wt);
            float4 o1 = make_float4((acc[4] * inv + b1.x) * wt, (acc[5] * inv + b1.y) * wt,
                                    (acc[6] * inv + b1.z) * wt, (acc[7] * inv + b1.w) * wt);
            *(float4*)&cat[(size_t)i * 80 + 40 + c * 8]     = o0;
            *(float4*)&cat[(size_t)i * 80 + 40 + c * 8 + 4] = o1;
        } else {
            float wc = *wc_p;
            int g = c - 5;
            float4 b0 = *(const float4*)&gcn_b2[g * 8];
            float4 b1 = *(const float4*)&gcn_b2[g * 8 + 4];
            float4 o0 = make_float4((acc[0] + b0.x) * wc, (acc[1] + b0.y) * wc,
                                    (acc[2] + b0.z) * wc, (acc[3] + b0.w) * wc);
            float4 o1 = make_float4((acc[4] + b1.x) * wc, (acc[5] + b1.y) * wc,
                                    (acc[6] + b1.z) * wc, (acc[7] + b1.w) * wc);
            *(float4*)&cat[(size_t)i * 80 + g * 8]     = o0;
            *(float4*)&cat[(size_t)i * 80 + g * 8 + 4] = o1;
        }
    }
}

// ---------------- host ------------------------------------------------------
extern "C" void kernel_launch(void* const* d_in, const int* in_sizes, int n_in,
                              void* d_out, int out_size, void* d_ws, size_t ws_size,
                              hipStream_t stream)
{
    const float* x        = (const float*)d_in[0];
    const int*   eidx     = (const int*)d_in[1];
    const float* gat_W1   = (const float*)d_in[2];
    const float* att_s1   = (const float*)d_in[3];
    const float* att_d1   = (const float*)d_in[4];
    const float* gat_b1   = (const float*)d_in[5];
    const float* gat_W2   = (const float*)d_in[6];
    const float* att_s2   = (const float*)d_in[7];
    const float* att_d2   = (const float*)d_in[8];
    const float* gat_b2   = (const float*)d_in[9];
    const float* gcn_W1   = (const float*)d_in[10];
    const float* gcn_b1   = (const float*)d_in[11];
    const float* gcn_W2   = (const float*)d_in[12];
    const float* gcn_b2   = (const float*)d_in[13];
    const float* lin_W    = (const float*)d_in[14];
    const float* lin_b    = (const float*)d_in[15];
    const float* wc_p     = (const float*)d_in[16];
    const float* wt_p     = (const float*)d_in[17];

    const int n = in_sizes[0] / F_IN;      // 50000
    const int e = in_sizes[1] / 2;         // 800000
    const int* src = eidx;
    const int* dst = eidx + e;
    const int NBUCK = (n + 127) >> 7;      // 391

    char* p = (char*)d_ws;
    auto alloc = [&](size_t bytes) -> void* {
        void* r = (void*)p;
        p += (bytes + 255) & ~(size_t)255;
        return r;
    };
    unsigned* counts  = (unsigned*)alloc((size_t)n * 4);
    unsigned* rs      = (unsigned*)alloc((size_t)(n + 1) * 4);
    unsigned* partials= (unsigned*)alloc(256 * 4);
    unsigned* bcnt    = (unsigned*)alloc((size_t)(NBUCK + 1) * 4);
    unsigned* csr_src = (unsigned*)alloc((size_t)e * 4);
    uint4*    wbf     = (uint4*)alloc(40 * 64 * 16);
    unsigned* bpair   = (unsigned*)alloc((size_t)NBUCK * BCAP * 4);  // now un-aliased
    uint2*    ovf     = (uint2*)alloc((size_t)OVCAP * 8);
    float* nrm     = (float*)alloc((size_t)n * 4);
    float* as1     = (float*)alloc((size_t)n * 4 * 4);
    float* ad1     = (float*)alloc((size_t)n * 4 * 4);
    float* as2     = (float*)alloc((size_t)n * 4);
    float* ad2     = (float*)alloc((size_t)n * 4);
    float* cat     = (float*)alloc((size_t)n * 80 * 4);   // agg2 out; earlier: hb
    unsigned* hg_b = (unsigned*)alloc((size_t)n * 40 * 4);
    float* xg      = (float*)alloc((size_t)n * F_IN * 4); // xgb bf16
    unsigned* gaccb= (unsigned*)alloc((size_t)n * 16 * 4);
    // aliases with disjoint lifetimes (stream-ordered):
    unsigned* hb    = (unsigned*)cat;     // [n][80] h1; written by merged kernel,
                                          // consumed by agg1 before agg2 writes cat
    unsigned* xgb   = (unsigned*)xg;
    unsigned* ovf_cnt = bcnt + NBUCK;

    const int NB = (n + 255) / 256;
    const int WB = (n + 3) / 4;
    const int SB = (e + SCHUNK - 1) / SCHUNK;
    const int G1 = (n + 63) / 64;

    // ---- W pre-pack (also zeroes bcnt + partials) ----
    wb_prep_kernel<<<40, 64, 0, stream>>>(gat_W1, gcn_W1, wbf, bcnt, NBUCK + 1, partials);

    // ---- gemm1 (blocks [0,G1)) || bucket scatter (blocks [G1,G1+SB)) ----
    scatter_gemm1_kernel<<<G1 + SB, 256, 0, stream>>>(
        src, dst, bcnt, bpair, ovf_cnt, ovf, e, NBUCK, G1,
        x, wbf, att_s1, att_d1, hb, as1, ad1, n);

    // ---- CSR build (count emits per-scan-block partials; write+place fused) ----
    bucket_count_kernel<<<NBUCK, 256, 0, stream>>>(bcnt, bpair, ovf_cnt, ovf, counts, partials, n);
    scan_partials_kernel<<<1, 256, 0, stream>>>(partials, rs, NB, n);
    scan_write_place_kernel<<<NB, 256, 0, stream>>>(counts, partials, rs, nrm,
                                                    bcnt, bpair, ovf_cnt, ovf,
                                                    csr_src, n, NBUCK);

    // ---- fused layer-1 aggregation (single-pass GAT softmax + GCN norm) ----
    agg1_fused_kernel<<<WB, 256, 0, stream>>>(hb, as1, ad1, nrm, rs, csr_src,
                                              gat_b1, gcn_b1, xgb, gaccb, n);

    // ---- layer-2 GEMMs into hg_b (gat gemm fuses logits2) ----
    gemm_tile_bb<32, 40, 128, 32, 40, 20><<<(n + 127) / 128, 320, 0, stream>>>(gaccb, gcn_W2, hg_b, n);
    gemm2_gat_kernel<<<(n + 127) / 128, 320, 0, stream>>>(xgb, gat_W2, att_s2, att_d2,
                                                          hg_b, as2, ad2, n);

    // ---- fused layer-2 aggregation -> cat ----
    agg2_fused_kernel<<<WB, 256, 0, stream>>>(hg_b, as2, ad2, nrm, rs, csr_src,
                                              gat_b2, gcn_b2, wc_p, wt_p, cat, n);

    // ---- head ----
    gemm_tile<80, 40, 128, 40><<<(n + 127) / 128, 320, 0, stream>>>(cat, lin_W, lin_b, (float*)d_out, n);
}